// Round 18
// baseline (360.492 us; speedup 1.0000x reference)
//
#include <hip/hip_runtime.h>
#include <hip/hip_bf16.h>

// SymbolicEncoder: conv(3->64,s2)+BN+ReLU -> conv(64->128,s2)+BN+ReLU ->
// conv(128->256,s2)+BN+ReLU -> 1x1 conv(256->64, padding (1,1)) -> VQ.
// z is (32,64,34,34); border px have z = bq = 0.
// Output (fp32 flat): symbols @ [0:2367488], loss @ 2367488, perp @ 2367489.
//
// R18: conv1 moved to matrix cores via tap-K=16 im2col MFMA (conv1MK).

#define BATCH 32

#define SYM_N 2367488
#define NPX   36992.0
#define CHW   73984
#define HW2   1156

static const unsigned long long NEED1 = 201392128ull;
static const unsigned long long NEED2 = 100728832ull;

typedef _Float16 half4 __attribute__((ext_vector_type(4)));
typedef _Float16 half8 __attribute__((ext_vector_type(8)));
typedef float f32x16 __attribute__((ext_vector_type(16)));

__device__ __forceinline__ float ldv(const float* p) { return *p; }
__device__ __forceinline__ float ldv(const __hip_bfloat16* p) { return __bfloat162float(*p); }
__device__ __forceinline__ float ldv(const _Float16* p) { return (float)(*p); }
__device__ __forceinline__ void stv(float* p, float v) { *p = v; }
__device__ __forceinline__ void stv(__hip_bfloat16* p, float v) { *p = __float2bfloat16(v); }
__device__ __forceinline__ void stv(_Float16* p, float v) { *p = (_Float16)v; }

__device__ __forceinline__ void st4(float* p, float a, float b, float c, float d) {
    float4 v; v.x = a; v.y = b; v.z = c; v.w = d;
    *(float4*)p = v;
}
__device__ __forceinline__ void st4(_Float16* p, float a, float b, float c, float d) {
    union { _Float16 h[4]; ushort4 u; } t;
    t.h[0] = (_Float16)a; t.h[1] = (_Float16)b; t.h[2] = (_Float16)c; t.h[3] = (_Float16)d;
    *(ushort4*)p = t.u;
}

// ---------------- init ----------------
__global__ void initStatsK(double* statd, int* counts) {
    int i = threadIdx.x + blockIdx.x * blockDim.x;
    if (i < 1537) statd[i] = 0.0;
    if (i < 512) counts[i] = 0;
}

// ---------------- codebook squared norms ----------------
__global__ void csqK(const float* __restrict__ cb, float* __restrict__ csqf,
                     double* __restrict__ csqd) {
    int k = threadIdx.x + blockIdx.x * blockDim.x;
    if (k < 512) {
        const float* r = cb + (size_t)k * 64;
        float s = 0.f; double sd = 0.0;
        for (int d = 0; d < 64; ++d) {
            s = fmaf(r[d], r[d], s);
            sd += (double)r[d] * (double)r[d];
        }
        csqf[k] = s; csqd[k] = sd;
    }
}

// ---------------- border codeword ----------------
__global__ void borderK(const double* __restrict__ csqd, int* __restrict__ kborder,
                        int* __restrict__ counts, double* __restrict__ lossAcc) {
    __shared__ double sV[512];
    __shared__ int sI[512];
    const int t = threadIdx.x;
    sV[t] = csqd[t]; sI[t] = t;
    __syncthreads();
    for (int st = 256; st > 0; st >>= 1) {
        if (t < st) {
            double v2 = sV[t + st]; int i2 = sI[t + st];
            if (v2 < sV[t] || (v2 == sV[t] && i2 < sI[t])) { sV[t] = v2; sI[t] = i2; }
        }
        __syncthreads();
    }
    if (t == 0) {
        int k = sI[0];
        *kborder = k;
        atomicAdd(&counts[k], 4224);
        atomicAdd(lossAcc, 4224.0 * sV[0]);
    }
}

// ---------------- fill symbols with border codeword ----------------
__global__ __launch_bounds__(256) void fillK(const int* __restrict__ kborder,
                                             const float* __restrict__ cb,
                                             float* __restrict__ out) {
    const int kb = *kborder;
    int E = blockIdx.x * 256 + threadIdx.x;
    if (E < SYM_N) {
        int d = (E / HW2) & 63;
        out[E] = cb[(size_t)kb * 64 + d];
    }
}

// ---------------- legacy conv 4x4 s2 (tier2 fallback conv1) ----------------
template<int CIN, int COUT, int IH, int IW, bool BN_IN, bool STORE, bool STATS,
         typename TI, typename TO>
__global__ __launch_bounds__(256) void conv4x4s2K(
    const TI* __restrict__ in, const float* __restrict__ wgt,
    const float* __restrict__ bias,
    const float* __restrict__ inScale, const float* __restrict__ inShift,
    TO* __restrict__ out, double* __restrict__ gSum, double* __restrict__ gSq)
{
    constexpr int OH = IH / 2, OW = IW / 2;
    constexpr int COLB = OW / 16;
    __shared__ float sIn[8 * 18 * 34];
    __shared__ float sW[128 * 64];
    __shared__ float sStat[128];

    const int tid = threadIdx.x;
    const int tx = tid & 15, ty = tid >> 4;
    const int cog = ty & 7, rg = ty >> 3;
    const int n = blockIdx.z;
    const int coBase = blockIdx.y * 64;
    const int brow = blockIdx.x / COLB, bcol = blockIdx.x % COLB;
    const int oh0 = brow * 8, ow0 = bcol * 16;
    const int ihb = oh0 * 2 - 1, iwb = ow0 * 2 - 1;

    float acc[8][4];
#pragma unroll
    for (int j = 0; j < 8; ++j)
#pragma unroll
        for (int r = 0; r < 4; ++r) acc[j][r] = 0.f;

    for (int c0 = 0; c0 < CIN; c0 += 8) {
        const int CC = (CIN - c0 < 8) ? (CIN - c0) : 8;
        for (int i = tid; i < 8 * 18 * 34; i += 256) {
            int ci = i / 612; int rem = i - ci * 612;
            int ih = rem / 34; int iw = rem - ih * 34;
            float v = 0.f;
            int gh = ihb + ih, gw = iwb + iw;
            if (ci < CC && (unsigned)gh < (unsigned)IH && (unsigned)gw < (unsigned)IW) {
                float r0 = ldv(&in[(((size_t)n * CIN + (c0 + ci)) * IH + gh) * IW + gw]);
                if (BN_IN) r0 = fmaxf(fmaf(r0, inScale[c0 + ci], inShift[c0 + ci]), 0.f);
                v = r0;
            }
            sIn[i] = v;
        }
        for (int i = tid; i < 8192; i += 256) {
            int co = i >> 7, r = i & 127;
            int ci = r >> 4, t = r & 15;
            float v = 0.f;
            if (ci < CC) v = wgt[(((size_t)(coBase + co)) * CIN + (c0 + ci)) * 16 + t];
            sW[r * 64 + (co ^ ((r & 7) << 3))] = v;
        }
        __syncthreads();
        for (int ci = 0; ci < CC; ++ci) {
#pragma unroll
            for (int kh = 0; kh < 4; ++kh) {
#pragma unroll
                for (int kw = 0; kw < 4; ++kw) {
                    const int tap = kh * 4 + kw;
                    const float* wp = sW + (ci * 16 + tap) * 64 + ((cog * 8) ^ ((tap & 7) << 3));
                    float4 wa = *(const float4*)wp;
                    float4 wb = *(const float4*)(wp + 4);
                    const float* ip = sIn + (ci * 18 + rg * 8 + kh) * 34 + tx * 2 + kw;
                    float wv[8] = {wa.x, wa.y, wa.z, wa.w, wb.x, wb.y, wb.z, wb.w};
                    float iv[4] = {ip[0], ip[68], ip[136], ip[204]};
#pragma unroll
                    for (int j = 0; j < 8; ++j)
#pragma unroll
                        for (int r = 0; r < 4; ++r)
                            acc[j][r] = fmaf(wv[j], iv[r], acc[j][r]);
                }
            }
        }
        __syncthreads();
    }

    if (STATS) {
        if (tid < 128) sStat[tid] = 0.f;
        __syncthreads();
    }

    const int coG = coBase + cog * 8;
#pragma unroll
    for (int j = 0; j < 8; ++j) {
        float bv = bias[coG + j];
        float s = 0.f, s2 = 0.f;
#pragma unroll
        for (int r = 0; r < 4; ++r) {
            float v = acc[j][r] + bv;
            if (STORE)
                stv(&out[(((size_t)n * COUT + coG + j) * OH + (oh0 + rg * 4 + r)) * OW + ow0 + tx], v);
            s += v; s2 = fmaf(v, v, s2);
        }
        if (STATS) {
#pragma unroll
            for (int m = 1; m < 16; m <<= 1) {
                s  += __shfl_xor(s, m, 64);
                s2 += __shfl_xor(s2, m, 64);
            }
            if (tx == 0) {
                atomicAdd(&sStat[cog * 8 + j], s);
                atomicAdd(&sStat[64 + cog * 8 + j], s2);
            }
        }
    }
    if (STATS) {
        __syncthreads();
        if (tid < 64) {
            atomicAdd(&gSum[coBase + tid], (double)sStat[tid]);
            atomicAdd(&gSq[coBase + tid],  (double)sStat[64 + tid]);
        }
    }
}

// ---------------- conv 4x4 s2, 8co x 8px tile (tier2) --------
template<int CIN, int COUT, int IH, int IW, int TH, int TW, bool BN_IN,
         bool STORE, bool STATS, typename TI, typename TO>
__global__ __launch_bounds__(256, 3) void conv8K(
    const TI* __restrict__ in, const float* __restrict__ wgt,
    const float* __restrict__ bias,
    const float* __restrict__ inScale, const float* __restrict__ inShift,
    TO* __restrict__ out, double* __restrict__ gSum, double* __restrict__ gSq)
{
    constexpr int OH = IH / 2, OW = IW / 2;
    constexpr int COLB = OW / TW;
    constexpr int SW = TW / 2;
    constexpr int ITH = TH * 2 + 2;
    constexpr int ITWP = TW * 2 + 4;
    constexpr int INSZ = 4 * ITH * ITWP;

    __shared__ float sIn[INSZ];
    __shared__ float sW[4 * 16 * 64];
    __shared__ float sStat[128];

    const int tid = threadIdx.x;
    const int s = tid & 31, cog = tid >> 5;
    const int sw = s & (SW - 1), sh = s / SW;
    const int n = blockIdx.z;
    const int coBase = blockIdx.y * 64;
    const int brow = blockIdx.x / COLB, bcol = blockIdx.x % COLB;
    const int oh0 = brow * TH, ow0 = bcol * TW;
    const int ihb = oh0 * 2 - 1, iwb = ow0 * 2 - 1;

    float acc[8][8];
#pragma unroll
    for (int c = 0; c < 8; ++c)
#pragma unroll
        for (int p = 0; p < 8; ++p) acc[c][p] = 0.f;

    for (int c0 = 0; c0 < CIN; c0 += 4) {
        const int CC = (CIN - c0 < 4) ? (CIN - c0) : 4;
        for (int i = tid; i < INSZ; i += 256) {
            int ci = i / (ITH * ITWP); int rem = i - ci * (ITH * ITWP);
            int ih = rem / ITWP; int iw = rem - ih * ITWP;
            float v = 0.f;
            int gh = ihb + ih, gw = iwb + iw;
            if (ci < CC && (unsigned)gh < (unsigned)IH && (unsigned)gw < (unsigned)IW) {
                float r0 = ldv(&in[(((size_t)n * CIN + (c0 + ci)) * IH + gh) * IW + gw]);
                if (BN_IN) r0 = fmaxf(fmaf(r0, inScale[c0 + ci], inShift[c0 + ci]), 0.f);
                v = r0;
            }
            sIn[i] = v;
        }
        for (int i = tid; i < 4096; i += 256) {
            int r = i >> 6, co = i & 63;
            int ci = r >> 4, tap = r & 15;
            float v = (ci < CC) ? wgt[(((size_t)(coBase + co)) * CIN + (c0 + ci)) * 16 + tap] : 0.f;
            sW[r * 64 + co] = v;
        }
        __syncthreads();
        for (int ci = 0; ci < CC; ++ci) {
#pragma unroll
            for (int kh = 0; kh < 4; ++kh) {
                float inv[4][8];
#pragma unroll
                for (int r = 0; r < 4; ++r) {
                    const float* ip = sIn + (ci * ITH + (sh * 4 + r) * 2 + kh) * ITWP + sw * 4;
                    float4 a = *(const float4*)ip;
                    float4 b = *(const float4*)(ip + 4);
                    inv[r][0] = a.x; inv[r][1] = a.y; inv[r][2] = a.z; inv[r][3] = a.w;
                    inv[r][4] = b.x; inv[r][5] = b.y; inv[r][6] = b.z; inv[r][7] = b.w;
                }
#pragma unroll
                for (int kw = 0; kw < 4; ++kw) {
                    const float* wp = sW + (ci * 16 + kh * 4 + kw) * 64 + cog * 8;
                    float4 wa = *(const float4*)wp;
                    float4 wb = *(const float4*)(wp + 4);
                    float wv[8] = {wa.x, wa.y, wa.z, wa.w, wb.x, wb.y, wb.z, wb.w};
#pragma unroll
                    for (int c = 0; c < 8; ++c)
#pragma unroll
                        for (int r = 0; r < 4; ++r)
#pragma unroll
                            for (int j = 0; j < 2; ++j)
                                acc[c][r * 2 + j] =
                                    fmaf(wv[c], inv[r][2 * j + kw], acc[c][r * 2 + j]);
                }
            }
        }
        __syncthreads();
    }

    if (STATS) {
        if (tid < 128) sStat[tid] = 0.f;
        __syncthreads();
    }

    const int coG = coBase + cog * 8;
#pragma unroll
    for (int c = 0; c < 8; ++c) {
        float bv = bias[coG + c];
        float s1 = 0.f, s2 = 0.f;
#pragma unroll
        for (int p = 0; p < 8; ++p) {
            float v = acc[c][p] + bv;
            int oh = oh0 + sh * 4 + (p >> 1), ow = ow0 + sw * 2 + (p & 1);
            if (STORE)
                stv(&out[(((size_t)n * COUT + coG + c) * OH + oh) * OW + ow], v);
            s1 += v; s2 = fmaf(v, v, s2);
        }
        if (STATS) {
#pragma unroll
            for (int m = 1; m < 32; m <<= 1) {
                s1 += __shfl_xor(s1, m, 64);
                s2 += __shfl_xor(s2, m, 64);
            }
            if ((tid & 31) == 0) {
                atomicAdd(&sStat[cog * 8 + c], s1);
                atomicAdd(&sStat[64 + cog * 8 + c], s2);
            }
        }
    }
    if (STATS) {
        __syncthreads();
        if (tid < 64) {
            atomicAdd(&gSum[coBase + tid], (double)sStat[tid]);
            atomicAdd(&gSq[coBase + tid],  (double)sStat[64 + tid]);
        }
    }
}

// ---------------- BN finalize ----------------
__global__ void bnFinK(const double* __restrict__ gSum, const double* __restrict__ gSq,
                       const float* __restrict__ g, const float* __restrict__ be,
                       float* __restrict__ scale, float* __restrict__ shift,
                       int C, double cnt)
{
    int c = threadIdx.x;
    if (c < C) {
        double m = gSum[c] / cnt;
        double v = gSq[c] / cnt - m * m;
        double sc = (double)g[c] / sqrt(v + 1e-5);
        scale[c] = (float)sc;
        shift[c] = (float)((double)be[c] - m * sc);
    }
}

// ---------------- weight repack: [co][ci][tap] f32 -> [tap][chunk][co][16] f16 ----
__global__ __launch_bounds__(256) void splitWK(
    const float* __restrict__ w, _Float16* __restrict__ wsOut, int CIN, int COUT)
{
    int CH = CIN >> 4;
    int total = 16 * CH * COUT * 16;
    for (int i = blockIdx.x * 256 + threadIdx.x; i < total; i += gridDim.x * 256) {
        int cil = i & 15; int r = i >> 4;
        int co = r % COUT; r /= COUT;
        int c = r % CH; int tap = r / CH;
        int ci = c * 16 + cil;
        wsOut[i] = (_Float16)w[((size_t)co * CIN + ci) * 16 + tap];
    }
}

// ---------------- w1 repack: [co][ci][tap] f32 -> [ci][co][16 taps] f16 ----
__global__ __launch_bounds__(256) void splitW1fK(
    const float* __restrict__ w1, _Float16* __restrict__ w1f)
{
    int i = blockIdx.x * 256 + threadIdx.x;   // 3072
    if (i < 3072) {
        int tap = i & 15; int r = i >> 4;
        int co = r & 63; int ci = r >> 6;
        w1f[i] = (_Float16)w1[((size_t)co * 3 + ci) * 16 + tap];
    }
}

// ---------------- wq repack for MFMA B-operand: [chunk c0][d][16 cil] f16 ----
__global__ __launch_bounds__(256) void splitWqfK(
    const float* __restrict__ wq, _Float16* __restrict__ wqf)
{
    int i = blockIdx.x * 256 + threadIdx.x;   // 16384
    int cil = i & 15; int r = i >> 4;
    int d = r & 63; int c0 = r >> 6;
    wqf[i] = (_Float16)wq[(size_t)d * 256 + c0 * 16 + cil];
}

// ---------------- codebook fp16 copy ----------------
__global__ __launch_bounds__(256) void cbhK(
    const float* __restrict__ cb, _Float16* __restrict__ cbh)
{
    int i = blockIdx.x * 256 + threadIdx.x;   // 32768
    cbh[i] = (_Float16)cb[i];
}

// ---------------- conv1 MFMA: tap-K=16 im2col (3->64, 256->128) ----------------
// block: 256 thr = 4 waves; wave mw = output row oh0+mw (32 ow px); NF=2
// covers all 64 co. A[px][tap] gathered from LDS tile [3 ci][10 ih][72 iw] f16;
// B = w1f [ci][co][16 taps] f16 (global, L1-resident). 3 ci -> 6 MFMA/wave.
__global__ __launch_bounds__(256) void conv1MK(
    const float* __restrict__ x, const _Float16* __restrict__ w1f,
    const float* __restrict__ bias,
    _Float16* __restrict__ out, double* __restrict__ gSum, double* __restrict__ gSq)
{
    constexpr int IH = 256, OH = 128, ITW = 72;
    __shared__ _Float16 sA[3 * 10 * ITW];   // 4320 B
    __shared__ float sStat[128];

    const int tid = threadIdx.x;
    const int l = tid & 63, mw = tid >> 6;
    const int lane31 = l & 31, hs = l >> 5;
    const int n = blockIdx.z;
    const int oh0 = (blockIdx.x >> 2) * 4;
    const int owB = (blockIdx.x & 3) * 32;
    const int ghBase = 2 * oh0 - 1, gwA = 2 * owB - 4;

    if (tid < 128) sStat[tid] = 0.f;

    // ---- stage x tile fp32 -> fp16: 3 ci x 10 ih x 18 quads ----
    for (int i = tid; i < 540; i += 256) {
        int q = i % 18; int r = i / 18; int ih = r % 10; int ci = r / 10;
        int gh = ghBase + ih;
        int gw0 = gwA + q * 4;
        float vs[4] = {0.f, 0.f, 0.f, 0.f};
        if ((unsigned)gh < (unsigned)IH) {
            const float* src = &x[(((size_t)n * 3 + ci) * IH + gh) * IH + gw0];
            if (gw0 >= 0 && gw0 + 3 < IH) {
                float4 f4 = *(const float4*)src;
                vs[0] = f4.x; vs[1] = f4.y; vs[2] = f4.z; vs[3] = f4.w;
            } else {
#pragma unroll
                for (int e = 0; e < 4; ++e) {
                    int gw = gw0 + e;
                    if ((unsigned)gw < (unsigned)IH) vs[e] = src[e];
                }
            }
        }
        union { _Float16 h[4]; ushort4 u; } t;
        t.h[0] = (_Float16)vs[0]; t.h[1] = (_Float16)vs[1];
        t.h[2] = (_Float16)vs[2]; t.h[3] = (_Float16)vs[3];
        *(ushort4*)&sA[(ci * 10 + ih) * ITW + q * 4] = t.u;
    }
    __syncthreads();

    f32x16 acc[2];
#pragma unroll
    for (int f = 0; f < 2; ++f)
#pragma unroll
        for (int j = 0; j < 16; ++j) acc[f][j] = 0.f;

#pragma unroll
    for (int ci = 0; ci < 3; ++ci) {
        // a[hs*8 + kh'*4 + kw] = sA[ci][2*mw + 2*hs + kh'][2*lane31 + 3 + kw]
        half8 a;
#pragma unroll
        for (int khp = 0; khp < 2; ++khp) {
            const _Float16* row = &sA[(ci * 10 + 2 * mw + 2 * hs + khp) * ITW + 2 * lane31 + 3];
#pragma unroll
            for (int kw = 0; kw < 4; ++kw) a[khp * 4 + kw] = row[kw];
        }
        const _Float16* bp = w1f + ((size_t)ci * 64 + lane31) * 16 + hs * 8;
#pragma unroll
        for (int f = 0; f < 2; ++f) {
            half8 b = *(const half8*)(bp + (size_t)f * 32 * 16);
            acc[f] = __builtin_amdgcn_mfma_f32_32x32x16_f16(a, b, acc[f], 0, 0, 0);
        }
    }

    const int oh = oh0 + mw;
#pragma unroll
    for (int f = 0; f < 2; ++f) {
        int co = f * 32 + lane31;
        float bv = bias[co];
        float s1 = 0.f, s2 = 0.f;
#pragma unroll
        for (int q = 0; q < 4; ++q) {
            float v0 = acc[f][q * 4 + 0] + bv;
            float v1 = acc[f][q * 4 + 1] + bv;
            float v2 = acc[f][q * 4 + 2] + bv;
            float v3 = acc[f][q * 4 + 3] + bv;
            s1 += (v0 + v1) + (v2 + v3);
            s2 = fmaf(v0, v0, s2); s2 = fmaf(v1, v1, s2);
            s2 = fmaf(v2, v2, s2); s2 = fmaf(v3, v3, s2);
            int ow = owB + q * 8 + hs * 4;
            st4(&out[(((size_t)n * 64 + co) * OH + oh) * OH + ow], v0, v1, v2, v3);
        }
        s1 += __shfl_xor(s1, 32, 64);
        s2 += __shfl_xor(s2, 32, 64);
        if (hs == 0) {
            atomicAdd(&sStat[co], s1);
            atomicAdd(&sStat[64 + co], s2);
        }
    }
    __syncthreads();
    if (tid < 64) {
        atomicAdd(&gSum[tid], (double)sStat[tid]);
        atomicAdd(&gSq[tid],  (double)sStat[64 + tid]);
    }
}

// ---------------- MFMA conv 4x4 s2 (4-row 8-wave blocks; conv2) ----------------
template<int CIN, int COUT, int IH, int NF, bool BN_IN, typename TO>
__global__ __launch_bounds__(512) void convMfmaK(
    const _Float16* __restrict__ in, const _Float16* __restrict__ wsplit,
    const float* __restrict__ bias,
    const float* __restrict__ inScale, const float* __restrict__ inShift,
    TO* __restrict__ out, double* __restrict__ gSum, double* __restrict__ gSq)
{
    constexpr int OH = IH / 2;
    constexpr int OWB = OH / 32;
    constexpr int CH = CIN / 16;
    constexpr int ROW = 20;
    constexpr int ITW = 72;
    __shared__ _Float16 sA[10 * ITW * ROW];
    __shared__ float sStat[2 * COUT];

    const int tid = threadIdx.x;
    const int l = tid & 63, wid = tid >> 6;
    const int lane31 = l & 31, hs = l >> 5;
    const int mw = wid & 3, nw = wid >> 2;
    const int n = blockIdx.z;
    const int ohB = (blockIdx.x / OWB) * 4;
    const int owB = (blockIdx.x % OWB) * 32;
    const int ghBase = 2 * ohB - 1, gwA = 2 * owB - 4;

    for (int i = tid; i < 2 * COUT; i += 512) sStat[i] = 0.f;

    f32x16 acc[NF];
#pragma unroll
    for (int f = 0; f < NF; ++f)
#pragma unroll
        for (int j = 0; j < 16; ++j) acc[f][j] = 0.f;

    for (int c = 0; c < CH; ++c) {
        __syncthreads();
        for (int i = tid; i < 10 * 18 * 16; i += 512) {
            int iwq = i % 18; int r = i / 18; int ih = r % 10; int cil = r / 10;
            int gh = ghBase + ih;
            int gw0 = gwA + iwq * 4;
            float scv = 1.f, shv = 0.f;
            if (BN_IN) { scv = inScale[c * 16 + cil]; shv = inShift[c * 16 + cil]; }
            float vs[4] = {0.f, 0.f, 0.f, 0.f};
            if ((unsigned)gh < (unsigned)IH) {
                const _Float16* src = &in[(((size_t)n * CIN + c * 16 + cil) * IH + gh) * IH + gw0];
                if (gw0 >= 0 && gw0 + 3 < IH) {
                    half4 q4 = *(const half4*)src;
#pragma unroll
                    for (int e = 0; e < 4; ++e) {
                        float v = (float)q4[e];
                        if (BN_IN) v = fmaxf(fmaf(v, scv, shv), 0.f);
                        vs[e] = v;
                    }
                } else {
#pragma unroll
                    for (int e = 0; e < 4; ++e) {
                        int gw = gw0 + e;
                        if ((unsigned)gw < (unsigned)IH) {
                            float v = (float)src[e];
                            if (BN_IN) v = fmaxf(fmaf(v, scv, shv), 0.f);
                            vs[e] = v;
                        }
                    }
                }
            }
            _Float16* dst = &sA[(ih * ITW + iwq * 4) * ROW + cil];
            dst[0]       = (_Float16)vs[0];
            dst[ROW]     = (_Float16)vs[1];
            dst[2 * ROW] = (_Float16)vs[2];
            dst[3 * ROW] = (_Float16)vs[3];
        }
        __syncthreads();
#pragma unroll
        for (int kh = 0; kh < 4; ++kh) {
#pragma unroll
            for (int kw = 0; kw < 4; ++kw) {
                const int ihX = 2 * mw + kh;
                const int off = (ihX * ITW + 2 * lane31 + kw + 3) * ROW + hs * 8;
                half4 a0 = *(const half4*)&sA[off];
                half4 a1 = *(const half4*)&sA[off + 4];
                half8 a;
                a[0] = a0[0]; a[1] = a0[1]; a[2] = a0[2]; a[3] = a0[3];
                a[4] = a1[0]; a[5] = a1[1]; a[6] = a1[2]; a[7] = a1[3];
                const _Float16* bp = wsplit
                    + (((size_t)(kh * 4 + kw) * CH + c) * COUT + nw * (NF * 32) + lane31) * 16
                    + hs * 8;
#pragma unroll
                for (int f = 0; f < NF; ++f) {
                    half8 b = *(const half8*)(bp + (size_t)f * 32 * 16);
                    acc[f] = __builtin_amdgcn_mfma_f32_32x32x16_f16(a, b, acc[f], 0, 0, 0);
                }
            }
        }
    }

    const int oh = ohB + mw;
#pragma unroll
    for (int f = 0; f < NF; ++f) {
        int co = nw * (NF * 32) + f * 32 + lane31;
        float bv = bias[co];
        float s1 = 0.f, s2 = 0.f;
#pragma unroll
        for (int q = 0; q < 4; ++q) {
            float v0 = acc[f][q * 4 + 0] + bv;
            float v1 = acc[f][q * 4 + 1] + bv;
            float v2 = acc[f][q * 4 + 2] + bv;
            float v3 = acc[f][q * 4 + 3] + bv;
            s1 += (v0 + v1) + (v2 + v3);
            s2 = fmaf(v0, v0, s2); s2 = fmaf(v1, v1, s2);
            s2 = fmaf(v2, v2, s2); s2 = fmaf(v3, v3, s2);
            int ow = owB + q * 8 + hs * 4;
            st4(&out[(((size_t)n * COUT + co) * OH + oh) * OH + ow], v0, v1, v2, v3);
        }
        s1 += __shfl_xor(s1, 32, 64);
        s2 += __shfl_xor(s2, 32, 64);
        if (hs == 0) {
            atomicAdd(&sStat[co], s1);
            atomicAdd(&sStat[COUT + co], s2);
        }
    }
    __syncthreads();
    for (int i = tid; i < COUT; i += 512) {
        atomicAdd(&gSum[i], (double)sStat[i]);
        atomicAdd(&gSq[i],  (double)sStat[COUT + i]);
    }
}

// ---------------- MFMA conv 4x4 s2 (1-row 4-wave blocks; conv3) ----------------
template<int CIN, int COUT, int IH, int OWBn, int NF, bool BN_IN, typename TO>
__global__ __launch_bounds__(256) void convM1RK(
    const _Float16* __restrict__ in, const _Float16* __restrict__ wsplit,
    const float* __restrict__ bias,
    const float* __restrict__ inScale, const float* __restrict__ inShift,
    TO* __restrict__ out, double* __restrict__ gSum, double* __restrict__ gSq)
{
    constexpr int OH = IH / 2;
    constexpr int CH = CIN / 16;
    constexpr int ROW = 20;
    constexpr int ITW = 72;
    __shared__ _Float16 sA[4 * ITW * ROW];
    __shared__ float sStat[2 * COUT];

    const int tid = threadIdx.x;
    const int l = tid & 63, nw = tid >> 6;
    const int lane31 = l & 31, hs = l >> 5;
    const int n = blockIdx.z;
    const int oh = blockIdx.x / OWBn;
    const int owB = (blockIdx.x % OWBn) * 32;
    const int ghBase = 2 * oh - 1, gwA = 2 * owB - 4;

    for (int i = tid; i < 2 * COUT; i += 256) sStat[i] = 0.f;

    f32x16 acc[NF];
#pragma unroll
    for (int f = 0; f < NF; ++f)
#pragma unroll
        for (int j = 0; j < 16; ++j) acc[f][j] = 0.f;

    for (int c = 0; c < CH; ++c) {
        __syncthreads();
        for (int i = tid; i < 4 * 18 * 16; i += 256) {
            int iwq = i % 18; int r = i / 18; int ih = r & 3; int cil = r >> 2;
            int gh = ghBase + ih;
            int gw0 = gwA + iwq * 4;
            float scv = 1.f, shv = 0.f;
            if (BN_IN) { scv = inScale[c * 16 + cil]; shv = inShift[c * 16 + cil]; }
            float vs[4] = {0.f, 0.f, 0.f, 0.f};
            if ((unsigned)gh < (unsigned)IH) {
                const _Float16* src = &in[(((size_t)n * CIN + c * 16 + cil) * IH + gh) * IH + gw0];
                if (gw0 >= 0 && gw0 + 3 < IH) {
                    half4 q4 = *(const half4*)src;
#pragma unroll
                    for (int e = 0; e < 4; ++e) {
                        float v = (float)q4[e];
                        if (BN_IN) v = fmaxf(fmaf(v, scv, shv), 0.f);
                        vs[e] = v;
                    }
                } else {
#pragma unroll
                    for (int e = 0; e < 4; ++e) {
                        int gw = gw0 + e;
                        if ((unsigned)gw < (unsigned)IH) {
                            float v = (float)src[e];
                            if (BN_IN) v = fmaxf(fmaf(v, scv, shv), 0.f);
                            vs[e] = v;
                        }
                    }
                }
            }
            _Float16* dst = &sA[(ih * ITW + iwq * 4) * ROW + cil];
            dst[0]       = (_Float16)vs[0];
            dst[ROW]     = (_Float16)vs[1];
            dst[2 * ROW] = (_Float16)vs[2];
            dst[3 * ROW] = (_Float16)vs[3];
        }
        __syncthreads();
#pragma unroll
        for (int kh = 0; kh < 4; ++kh) {
#pragma unroll
            for (int kw = 0; kw < 4; ++kw) {
                const int off = (kh * ITW + 2 * lane31 + kw + 3) * ROW + hs * 8;
                half4 a0 = *(const half4*)&sA[off];
                half4 a1 = *(const half4*)&sA[off + 4];
                half8 a;
                a[0] = a0[0]; a[1] = a0[1]; a[2] = a0[2]; a[3] = a0[3];
                a[4] = a1[0]; a[5] = a1[1]; a[6] = a1[2]; a[7] = a1[3];
                const _Float16* bp = wsplit
                    + (((size_t)(kh * 4 + kw) * CH + c) * COUT + nw * (NF * 32) + lane31) * 16
                    + hs * 8;
#pragma unroll
                for (int f = 0; f < NF; ++f) {
                    half8 b = *(const half8*)(bp + (size_t)f * 32 * 16);
                    acc[f] = __builtin_amdgcn_mfma_f32_32x32x16_f16(a, b, acc[f], 0, 0, 0);
                }
            }
        }
    }

#pragma unroll
    for (int f = 0; f < NF; ++f) {
        int co = nw * (NF * 32) + f * 32 + lane31;
        float bv = bias[co];
        float s1 = 0.f, s2 = 0.f;
#pragma unroll
        for (int q = 0; q < 4; ++q) {
            float v0 = acc[f][q * 4 + 0] + bv;
            float v1 = acc[f][q * 4 + 1] + bv;
            float v2 = acc[f][q * 4 + 2] + bv;
            float v3 = acc[f][q * 4 + 3] + bv;
            s1 += (v0 + v1) + (v2 + v3);
            s2 = fmaf(v0, v0, s2); s2 = fmaf(v1, v1, s2);
            s2 = fmaf(v2, v2, s2); s2 = fmaf(v3, v3, s2);
            int ow = owB + q * 8 + hs * 4;
            st4(&out[(((size_t)n * COUT + co) * OH + oh) * OH + ow], v0, v1, v2, v3);
        }
        s1 += __shfl_xor(s1, 32, 64);
        s2 += __shfl_xor(s2, 32, 64);
        if (hs == 0) {
            atomicAdd(&sStat[co], s1);
            atomicAdd(&sStat[COUT + co], s2);
        }
    }
    __syncthreads();
    for (int i = tid; i < COUT; i += 256) {
        atomicAdd(&gSum[i], (double)sStat[i]);
        atomicAdd(&gSq[i],  (double)sStat[COUT + i]);
    }
}

// ---------------- fused head v4: MFMA z-GEMM + score-GEMM ----------------
__global__ __launch_bounds__(512) void headK4(
    const _Float16* __restrict__ y3h, const _Float16* __restrict__ wqf,
    const float* __restrict__ bq,
    const float* __restrict__ sc3, const float* __restrict__ sh3,
    const float* __restrict__ cb, const _Float16* __restrict__ cbh,
    const float* __restrict__ csqf,
    float* __restrict__ out, int* __restrict__ counts,
    double* __restrict__ lossAcc)
{
    __shared__ _Float16 sH[32 * 264];
    __shared__ float    sZ[32 * 68];
    __shared__ _Float16 sZh[32 * 72];
    __shared__ float    sCS[8 * 32];
    __shared__ int      sCI[8 * 32];

    const int tid = threadIdx.x;
    const int w = tid >> 6;
    const int l = tid & 63;
    const int lane31 = l & 31, hs = l >> 5;
    const int blk = blockIdx.x;
    const int n = (blk * 32) >> 10;
    const int hw0 = (blk * 32) & 1023;

    {
        const int px = tid & 31, cg = tid >> 5;
#pragma unroll
        for (int k = 0; k < 16; ++k) {
            int c = cg + 16 * k;
            float v = (float)y3h[(((size_t)n * 256 + c) << 10) + hw0 + px];
            v = fmaxf(fmaf(v, sc3[c], sh3[c]), 0.f);
            sH[px * 264 + c] = (_Float16)v;
        }
    }
    __syncthreads();

    if (w < 2) {
        f32x16 za;
#pragma unroll
        for (int j = 0; j < 16; ++j) za[j] = 0.f;
#pragma unroll
        for (int c0 = 0; c0 < 16; ++c0) {
            half8 a = *(const half8*)&sH[lane31 * 264 + c0 * 16 + hs * 8];
            const _Float16* bp = wqf + ((size_t)(c0 * 64) + 32 * w + lane31) * 16 + hs * 8;
            half8 b = *(const half8*)bp;
            za = __builtin_amdgcn_mfma_f32_32x32x16_f16(a, b, za, 0, 0, 0);
        }
        const int d = 32 * w + lane31;
        const float bqv = bq[d];
#pragma unroll
        for (int j = 0; j < 16; ++j) {
            int row = (j & 3) + 8 * (j >> 2) + 4 * hs;
            float zv = za[j] + bqv;
            sZ[row * 68 + d] = zv;
            sZh[row * 72 + d] = (_Float16)zv;
        }
    }
    __syncthreads();

    f32x16 acc0, acc1;
#pragma unroll
    for (int j = 0; j < 16; ++j) { acc0[j] = 0.f; acc1[j] = 0.f; }
#pragma unroll
    for (int ks = 0; ks < 4; ++ks) {
        half8 a = *(const half8*)&sZh[lane31 * 72 + ks * 16 + hs * 8];
        const _Float16* b0 = cbh + ((size_t)(64 * w + lane31) << 6) + ks * 16 + hs * 8;
        const _Float16* b1 = b0 + (32 << 6);
        acc0 = __builtin_amdgcn_mfma_f32_32x32x16_f16(a, *(const half8*)b0, acc0, 0, 0, 0);
        acc1 = __builtin_amdgcn_mfma_f32_32x32x16_f16(a, *(const half8*)b1, acc1, 0, 0, 0);
    }
    const int cw0 = 64 * w + lane31;
    const float cs0 = csqf[cw0], cs1 = csqf[cw0 + 32];
#pragma unroll
    for (int j = 0; j < 16; ++j) {
        int row = (j & 3) + 8 * (j >> 2) + 4 * hs;
        float s = cs0 - 2.f * acc0[j];
        int idx = cw0;
        float s1 = cs1 - 2.f * acc1[j];
        if (s1 < s) { s = s1; idx = cw0 + 32; }
#pragma unroll
        for (int m = 1; m < 32; m <<= 1) {
            float so = __shfl_xor(s, m, 32);
            int io = __shfl_xor(idx, m, 32);
            if (so < s || (so == s && io < idx)) { s = so; idx = io; }
        }
        if (lane31 == 0) { sCS[w * 32 + row] = s; sCI[w * 32 + row] = idx; }
    }
    __syncthreads();

    if (w == 0 && l < 32) {
        const int px = l;
        float best = sCS[px]; int bidx = sCI[px];
#pragma unroll
        for (int g = 1; g < 8; ++g) {
            float b = sCS[g * 32 + px]; int i = sCI[g * 32 + px];
            if (b < best || (b == best && i < bidx)) { best = b; bidx = i; }
        }
        atomicAdd(&counts[bidx], 1);

        const int hw = hw0 + px;
        const int hh = hw >> 5, ww = hw & 31;
        const int obase = n * CHW + (hh + 1) * 34 + (ww + 1);
        const float4* qp = (const float4*)(cb + ((size_t)bidx << 6));
        const float4* zrow = (const float4*)(sZ + px * 68);
        float sq = 0.f;
#pragma unroll
        for (int q = 0; q < 16; ++q) {
            float4 c4 = qp[q];
            float4 z4 = zrow[q];
            float d0 = c4.x - z4.x, d1 = c4.y - z4.y;
            float d2 = c4.z - z4.z, d3 = c4.w - z4.w;
            sq = fmaf(d0, d0, sq); sq = fmaf(d1, d1, sq);
            sq = fmaf(d2, d2, sq); sq = fmaf(d3, d3, sq);
            out[obase + (4 * q + 0) * HW2] = c4.x;
            out[obase + (4 * q + 1) * HW2] = c4.y;
            out[obase + (4 * q + 2) * HW2] = c4.z;
            out[obase + (4 * q + 3) * HW2] = c4.w;
        }
#pragma unroll
        for (int m = 1; m < 32; m <<= 1) sq += __shfl_xor(sq, m, 32);
        if (l == 0) atomicAdd(lossAcc, (double)sq);
    }
}

// ---------------- tier2: 1x1 conv kernel ----------------
__global__ __launch_bounds__(128) void convqK(
    const float* __restrict__ y3, const float* __restrict__ wq,
    const float* __restrict__ bq,
    const float* __restrict__ sc3, const float* __restrict__ sh3,
    float* __restrict__ z)
{
    __shared__ float sWq[64 * 68];
    __shared__ float sS[64], sH[64];
    const int tid = threadIdx.x;
    const int px = blockIdx.x * 128 + tid;
    const int n = px >> 10, hw = px & 1023;

    float accv[64];
#pragma unroll
    for (int d = 0; d < 64; ++d) accv[d] = 0.f;

    const float* base = y3 + (((size_t)n * 256) << 10) + hw;
    for (int c0 = 0; c0 < 256; c0 += 64) {
        __syncthreads();
        for (int i = tid; i < 4096; i += 128) {
            int c = i & 63, d = i >> 6;
            sWq[c * 68 + d] = wq[(size_t)d * 256 + c0 + c];
        }
        if (tid < 64) { sS[tid] = sc3[c0 + tid]; sH[tid] = sh3[c0 + tid]; }
        __syncthreads();
        for (int c = 0; c < 64; ++c) {
            float h = base[(size_t)(c0 + c) << 10];
            h = fmaxf(fmaf(h, sS[c], sH[c]), 0.f);
            const float4* wrow = (const float4*)(sWq + c * 68);
#pragma unroll
            for (int q = 0; q < 16; ++q) {
                float4 w4 = wrow[q];
                accv[4*q+0] = fmaf(h, w4.x, accv[4*q+0]);
                accv[4*q+1] = fmaf(h, w4.y, accv[4*q+1]);
                accv[4*q+2] = fmaf(h, w4.z, accv[4*q+2]);
                accv[4*q+3] = fmaf(h, w4.w, accv[4*q+3]);
            }
        }
    }
    float* zo = z + (size_t)px * 64;
    const float4* bq4 = (const float4*)bq;
#pragma unroll
    for (int q = 0; q < 16; ++q) {
        float4 b4 = bq4[q];
        float4 v;
        v.x = accv[4*q+0] + b4.x; v.y = accv[4*q+1] + b4.y;
        v.z = accv[4*q+2] + b4.z; v.w = accv[4*q+3] + b4.w;
        ((float4*)zo)[q] = v;
    }
}

// ---------------- tier2: vq kernel ----------------
__global__ __launch_bounds__(256) void vqK(
    const float* __restrict__ z, const float* __restrict__ cb,
    const float* __restrict__ csqf, float* __restrict__ out,
    int* __restrict__ counts, double* __restrict__ lossAcc)
{
    const int tid = threadIdx.x;
    const int lane = tid & 63;
    const int grp = tid >> 6;
    const int px = blockIdx.x * 64 + lane;

    float zr[64];
    const float4* zp = (const float4*)(z + (size_t)px * 64);
#pragma unroll
    for (int q = 0; q < 16; ++q) {
        float4 t = zp[q];
        zr[4*q] = t.x; zr[4*q+1] = t.y; zr[4*q+2] = t.z; zr[4*q+3] = t.w;
    }

    const int kbase = grp * 128;
    float best = 3.4e38f; int bidx = kbase;
    for (int kk = 0; kk < 128; ++kk) {
        const float4* crow = (const float4*)(cb + (size_t)(kbase + kk) * 64);
        float d0 = 0.f, d1 = 0.f, d2 = 0.f, d3 = 0.f;
#pragma unroll
        for (int q = 0; q < 16; ++q) {
            float4 c4 = crow[q];
            d0 = fmaf(zr[4*q+0], c4.x, d0);
            d1 = fmaf(zr[4*q+1], c4.y, d1);
            d2 = fmaf(zr[4*q+2], c4.z, d2);
            d3 = fmaf(zr[4*q+3], c4.w, d3);
        }
        float dot = (d0 + d1) + (d2 + d3);
        float score = csqf[kbase + kk] - 2.0f * dot;
        if (score < best) { best = score; bidx = kbase + kk; }
    }

    __shared__ float sB[256];
    __shared__ int   sI[256];
    sB[tid] = best; sI[tid] = bidx;
    __syncthreads();
    if (grp == 0) {
#pragma unroll
        for (int g = 1; g < 4; ++g) {
            float b = sB[lane + 64 * g]; int i = sI[lane + 64 * g];
            if (b < best || (b == best && i < bidx)) { best = b; bidx = i; }
        }
        atomicAdd(&counts[bidx], 1);

        const int n = px >> 10, hw = px & 1023;
        const int h = hw >> 5, w = hw & 31;
        const int obase = n * CHW + (h + 1) * 34 + (w + 1);
        const float4* qp = (const float4*)(cb + (size_t)bidx * 64);
        float sq = 0.f;
#pragma unroll
        for (int q = 0; q < 16; ++q) {
            float4 c4 = qp[q];
            float vv[4] = {c4.x, c4.y, c4.z, c4.w};
#pragma unroll
            for (int j = 0; j < 4; ++j) {
                int d = 4 * q + j;
                float df = vv[j] - zr[d];
                sq = fmaf(df, df, sq);
                out[obase + d * HW2] = vv[j];
            }
        }
#pragma unroll
        for (int m = 1; m < 64; m <<= 1) sq += __shfl_xor(sq, m, 64);
        if (lane == 0) atomicAdd(lossAcc, (double)sq);
    }
}

// ---------------- loss + perplexity ----------------
__global__ void finalizeK(const int* __restrict__ counts,
                          const double* __restrict__ lossAcc,
                          float* __restrict__ out)
{
    const int tid = threadIdx.x;
    double ent = 0.0;
    for (int k = tid; k < 512; k += 64) {
        double p = (double)counts[k] / NPX;
        ent -= p * log(p + 1e-10);
    }
#pragma unroll
    for (int m = 1; m < 64; m <<= 1) ent += __shfl_xor(ent, m, 64);
    if (tid == 0) {
        out[SYM_N]     = (float)(1.25 * lossAcc[0] / (double)SYM_N);
        out[SYM_N + 1] = (float)exp(ent);
    }
}

// ---------------- fallback: zero + sentinel ----------------
__global__ __launch_bounds__(256) void zeroOutK(float* __restrict__ out, int n) {
    int i = blockIdx.x * 256 + threadIdx.x;
    if (i < n) out[i] = 0.0f;
}
__global__ void sentinelK(float* out, float lossv, float perpv) {
    if (threadIdx.x == 0) { out[SYM_N] = lossv; out[SYM_N + 1] = perpv; }
}

// =======================================================================
// primary path
// =======================================================================
static void run_mfma(void* const* d_in, float* out, char* ws, hipStream_t stream)
{
    const float* x   = (const float*)d_in[0];
    const float* w1  = (const float*)d_in[1];
    const float* b1  = (const float*)d_in[2];
    const float* g1  = (const float*)d_in[3];
    const float* be1 = (const float*)d_in[4];
    const float* w2  = (const float*)d_in[5];
    const float* b2  = (const float*)d_in[6];
    const float* g2  = (const float*)d_in[7];
    const float* be2 = (const float*)d_in[8];
    const float* w3  = (const float*)d_in[9];
    const float* b3  = (const float*)d_in[10];
    const float* g3  = (const float*)d_in[11];
    const float* be3 = (const float*)d_in[12];
    const float* wq  = (const float*)d_in[13];
    const float* bq  = (const float*)d_in[14];
    const float* cb  = (const float*)d_in[15];

    double* statd  = (double*)(ws);
    float*  sscale = (float*)(ws + 16384);
    int*    counts = (int*)(ws + 24576);
    float*  csqf   = (float*)(ws + 28672);
    double* csqd   = (double*)(ws + 30720);
    int*    kbord  = (int*)(ws + 34816);
    double* lossAcc = statd + 1536;

    char* A0 = ws + 65536;
    _Float16* y1h = (_Float16*)A0;                         // 64MB
    _Float16* y2h = (_Float16*)(A0 + 67108864ull);         // 32MB
    _Float16* y3h = (_Float16*)(A0 + 100663296ull);        // 16MB
    _Float16* w2s = (_Float16*)(A0 + 117440512ull);        // 256KB
    _Float16* w3s = (_Float16*)(A0 + 117702656ull);        // 1MB
    _Float16* wqf = (_Float16*)(A0 + 118751232ull);        // 32KB
    _Float16* cbh = (_Float16*)(A0 + 118800384ull);        // 64KB
    _Float16* w1f = (_Float16*)(A0 + 118865920ull);        // 6KB

    initStatsK<<<7, 256, 0, stream>>>(statd, counts);
    csqK<<<2, 256, 0, stream>>>(cb, csqf, csqd);
    borderK<<<1, 512, 0, stream>>>(csqd, kbord, counts, lossAcc);
    fillK<<<(SYM_N + 255) / 256, 256, 0, stream>>>(kbord, cb, out);
    splitWK<<<512, 256, 0, stream>>>(w2, w2s, 64, 128);
    splitWK<<<2048, 256, 0, stream>>>(w3, w3s, 128, 256);
    splitWqfK<<<64, 256, 0, stream>>>(wq, wqf);
    cbhK<<<128, 256, 0, stream>>>(cb, cbh);
    splitW1fK<<<12, 256, 0, stream>>>(w1, w1f);

    // conv1: tap-K MFMA, grid = 32 rowblocks*4 owb x 32 n
    conv1MK<<<dim3(128, 1, BATCH), 256, 0, stream>>>(
        x, w1f, b1, y1h, statd + 0, statd + 256);
    bnFinK<<<1, 256, 0, stream>>>(statd + 0, statd + 256, g1, be1,
                                  sscale + 0, sscale + 256, 64, 524288.0);

    convMfmaK<64, 128, 128, 2, true, _Float16>
        <<<dim3(32, 1, BATCH), 512, 0, stream>>>(
        y1h, w2s, b2, sscale + 0, sscale + 256, y2h, statd + 512, statd + 768);
    bnFinK<<<1, 256, 0, stream>>>(statd + 512, statd + 768, g2, be2,
                                  sscale + 512, sscale + 768, 128, 131072.0);

    convM1RK<128, 256, 64, 1, 2, true, _Float16>
        <<<dim3(32, 1, BATCH), 256, 0, stream>>>(
        y2h, w3s, b3, sscale + 512, sscale + 768, y3h, statd + 1024, statd + 1280);
    bnFinK<<<1, 256, 0, stream>>>(statd + 1024, statd + 1280, g3, be3,
                                  sscale + 1024, sscale + 1280, 256, 32768.0);

    headK4<<<1024, 512, 0, stream>>>(y3h, wqf, bq, sscale + 1024, sscale + 1280,
                                     cb, cbh, csqf, out, counts, lossAcc);
    finalizeK<<<1, 64, 0, stream>>>(counts, lossAcc, out);
}

// =======================================================================
// fallback tier2: single-pass bf16 storage (proven structure)
// =======================================================================
static void run_fast_bf16(void* const* d_in, float* out, char* ws, hipStream_t stream)
{
    const float* x   = (const float*)d_in[0];
    const float* w1  = (const float*)d_in[1];
    const float* b1  = (const float*)d_in[2];
    const float* g1  = (const float*)d_in[3];
    const float* be1 = (const float*)d_in[4];
    const float* w2  = (const float*)d_in[5];
    const float* b2  = (const float*)d_in[6];
    const float* g2  = (const float*)d_in[7];
    const float* be2 = (const float*)d_in[8];
    const float* w3  = (const float*)d_in[9];
    const float* b3  = (const float*)d_in[10];
    const float* g3  = (const float*)d_in[11];
    const float* be3 = (const float*)d_in[12];
    const float* wq  = (const float*)d_in[13];
    const float* bq  = (const float*)d_in[14];
    const float* cb  = (const float*)d_in[15];

    double* statd  = (double*)(ws);
    float*  sscale = (float*)(ws + 16384);
    int*    counts = (int*)(ws + 24576);
    float*  csqf   = (float*)(ws + 28672);
    double* csqd   = (double*)(ws + 30720);
    int*    kbord  = (int*)(ws + 34816);
    double* lossAcc = statd + 1536;

    __hip_bfloat16* y1 = (__hip_bfloat16*)(ws + 65536);
    __hip_bfloat16* y2 = (__hip_bfloat16*)(ws + 65536 + 67108864ull);
    float* y3 = (float*)(ws + 65536);
    float* z  = (float*)(ws + 65536 + 33554432ull);

    initStatsK<<<7, 256, 0, stream>>>(statd, counts);
    csqK<<<2, 256, 0, stream>>>(cb, csqf, csqd);
    borderK<<<1, 512, 0, stream>>>(csqd, kbord, counts, lossAcc);
    fillK<<<(SYM_N + 255) / 256, 256, 0, stream>>>(kbord, cb, out);

    conv4x4s2K<3, 64, 256, 256, false, true, true, float, __hip_bfloat16>
        <<<dim3(128, 1, BATCH), 256, 0, stream>>>(
        x, w1, b1, nullptr, nullptr, y1, statd + 0, statd + 256);
    bnFinK<<<1, 256, 0, stream>>>(statd + 0, statd + 256, g1, be1,
                                  sscale + 0, sscale + 256, 64, 524288.0);

    conv8K<64, 128, 128, 128, 8, 32, true, true, true, __hip_bfloat16, __hip_bfloat16>
        <<<dim3(16, 2, BATCH), 256, 0, stream>>>(
        y1, w2, b2, sscale + 0, sscale + 256, y2, statd + 512, statd + 768);
    bnFinK<<<1, 256, 0, stream>>>(statd + 512, statd + 768, g2, be2,
                                  sscale + 512, sscale + 768, 128, 131072.0);

    conv8K<128, 256, 64, 64, 16, 16, true, true, true, __hip_bfloat16, float>
        <<<dim3(4, 4, BATCH), 256, 0, stream>>>(
        y2, w3, b3, sscale + 512, sscale + 768, y3, statd + 1024, statd + 1280);
    bnFinK<<<1, 256, 0, stream>>>(statd + 1024, statd + 1280, g3, be3,
                                  sscale + 1024, sscale + 1280, 256, 32768.0);

    convqK<<<256, 128, 0, stream>>>(y3, wq, bq, sscale + 1024, sscale + 1280, z);
    vqK<<<512, 256, 0, stream>>>(z, cb, csqf, out, counts, lossAcc);
    finalizeK<<<1, 64, 0, stream>>>(counts, lossAcc, out);
}

extern "C" void kernel_launch(void* const* d_in, const int* in_sizes, int n_in,
                              void* d_out, int out_size, void* d_ws, size_t ws_size,
                              hipStream_t stream)
{
    float* out = (float*)d_out;
    char* ws = (char*)d_ws;

    if (ws_size >= NEED1) {
        run_mfma(d_in, out, ws, stream);
    } else if (ws_size >= NEED2) {
        run_fast_bf16(d_in, out, ws, stream);
    } else {
        zeroOutK<<<(SYM_N + 2 + 255) / 256, 256, 0, stream>>>(out, SYM_N + 2);
        sentinelK<<<1, 64, 0, stream>>>(out, -4444.0f, -5555.0f);
    }
}

// Round 19
// 278.358 us; speedup vs baseline: 1.2951x; 1.2951x over previous
//
#include <hip/hip_runtime.h>
#include <hip/hip_bf16.h>

// SymbolicEncoder: conv(3->64,s2)+BN+ReLU -> conv(64->128,s2)+BN+ReLU ->
// conv(128->256,s2)+BN+ReLU -> 1x1 conv(256->64, padding (1,1)) -> VQ.
// Output (fp32 flat): symbols @ [0:2367488], loss @ 2367488, perp @ 2367489.
//
// R19: BN stats via slot-spread fp32 atomics (16 slots) instead of contended
// fp64 global atomics; bnFinSlotK reduces slots in double.

#define BATCH 32
#define NSLOT 16

#define SYM_N 2367488
#define NPX   36992.0
#define CHW   73984
#define HW2   1156

static const unsigned long long NEED1 = 201392128ull;
static const unsigned long long NEED2 = 100728832ull;

typedef _Float16 half4 __attribute__((ext_vector_type(4)));
typedef _Float16 half8 __attribute__((ext_vector_type(8)));
typedef float f32x16 __attribute__((ext_vector_type(16)));

__device__ __forceinline__ float ldv(const float* p) { return *p; }
__device__ __forceinline__ float ldv(const __hip_bfloat16* p) { return __bfloat162float(*p); }
__device__ __forceinline__ float ldv(const _Float16* p) { return (float)(*p); }
__device__ __forceinline__ void stv(float* p, float v) { *p = v; }
__device__ __forceinline__ void stv(__hip_bfloat16* p, float v) { *p = __float2bfloat16(v); }
__device__ __forceinline__ void stv(_Float16* p, float v) { *p = (_Float16)v; }

__device__ __forceinline__ void st4(float* p, float a, float b, float c, float d) {
    float4 v; v.x = a; v.y = b; v.z = c; v.w = d;
    *(float4*)p = v;
}
__device__ __forceinline__ void st4(_Float16* p, float a, float b, float c, float d) {
    union { _Float16 h[4]; ushort4 u; } t;
    t.h[0] = (_Float16)a; t.h[1] = (_Float16)b; t.h[2] = (_Float16)c; t.h[3] = (_Float16)d;
    *(ushort4*)p = t.u;
}

// ---------------- init ----------------
__global__ void initStatsK(double* statd, int* counts) {
    int i = threadIdx.x + blockIdx.x * blockDim.x;
    if (i < 1537) statd[i] = 0.0;
    if (i < 512) counts[i] = 0;
}

__global__ __launch_bounds__(256) void zeroSlotsK(float* __restrict__ p, int n) {
    int i = blockIdx.x * 256 + threadIdx.x;
    if (i < n) p[i] = 0.f;
}

// ---------------- codebook squared norms ----------------
__global__ void csqK(const float* __restrict__ cb, float* __restrict__ csqf,
                     double* __restrict__ csqd) {
    int k = threadIdx.x + blockIdx.x * blockDim.x;
    if (k < 512) {
        const float* r = cb + (size_t)k * 64;
        float s = 0.f; double sd = 0.0;
        for (int d = 0; d < 64; ++d) {
            s = fmaf(r[d], r[d], s);
            sd += (double)r[d] * (double)r[d];
        }
        csqf[k] = s; csqd[k] = sd;
    }
}

// ---------------- border codeword ----------------
__global__ void borderK(const double* __restrict__ csqd, int* __restrict__ kborder,
                        int* __restrict__ counts, double* __restrict__ lossAcc) {
    __shared__ double sV[512];
    __shared__ int sI[512];
    const int t = threadIdx.x;
    sV[t] = csqd[t]; sI[t] = t;
    __syncthreads();
    for (int st = 256; st > 0; st >>= 1) {
        if (t < st) {
            double v2 = sV[t + st]; int i2 = sI[t + st];
            if (v2 < sV[t] || (v2 == sV[t] && i2 < sI[t])) { sV[t] = v2; sI[t] = i2; }
        }
        __syncthreads();
    }
    if (t == 0) {
        int k = sI[0];
        *kborder = k;
        atomicAdd(&counts[k], 4224);
        atomicAdd(lossAcc, 4224.0 * sV[0]);
    }
}

// ---------------- fill symbols with border codeword ----------------
__global__ __launch_bounds__(256) void fillK(const int* __restrict__ kborder,
                                             const float* __restrict__ cb,
                                             float* __restrict__ out) {
    const int kb = *kborder;
    int E = blockIdx.x * 256 + threadIdx.x;
    if (E < SYM_N) {
        int d = (E / HW2) & 63;
        out[E] = cb[(size_t)kb * 64 + d];
    }
}

// ---------------- legacy conv 4x4 s2 (tier2 fallback conv1) ----------------
template<int CIN, int COUT, int IH, int IW, bool BN_IN, bool STORE, bool STATS,
         typename TI, typename TO>
__global__ __launch_bounds__(256) void conv4x4s2K(
    const TI* __restrict__ in, const float* __restrict__ wgt,
    const float* __restrict__ bias,
    const float* __restrict__ inScale, const float* __restrict__ inShift,
    TO* __restrict__ out, double* __restrict__ gSum, double* __restrict__ gSq)
{
    constexpr int OH = IH / 2, OW = IW / 2;
    constexpr int COLB = OW / 16;
    __shared__ float sIn[8 * 18 * 34];
    __shared__ float sW[128 * 64];
    __shared__ float sStat[128];

    const int tid = threadIdx.x;
    const int tx = tid & 15, ty = tid >> 4;
    const int cog = ty & 7, rg = ty >> 3;
    const int n = blockIdx.z;
    const int coBase = blockIdx.y * 64;
    const int brow = blockIdx.x / COLB, bcol = blockIdx.x % COLB;
    const int oh0 = brow * 8, ow0 = bcol * 16;
    const int ihb = oh0 * 2 - 1, iwb = ow0 * 2 - 1;

    float acc[8][4];
#pragma unroll
    for (int j = 0; j < 8; ++j)
#pragma unroll
        for (int r = 0; r < 4; ++r) acc[j][r] = 0.f;

    for (int c0 = 0; c0 < CIN; c0 += 8) {
        const int CC = (CIN - c0 < 8) ? (CIN - c0) : 8;
        for (int i = tid; i < 8 * 18 * 34; i += 256) {
            int ci = i / 612; int rem = i - ci * 612;
            int ih = rem / 34; int iw = rem - ih * 34;
            float v = 0.f;
            int gh = ihb + ih, gw = iwb + iw;
            if (ci < CC && (unsigned)gh < (unsigned)IH && (unsigned)gw < (unsigned)IW) {
                float r0 = ldv(&in[(((size_t)n * CIN + (c0 + ci)) * IH + gh) * IW + gw]);
                if (BN_IN) r0 = fmaxf(fmaf(r0, inScale[c0 + ci], inShift[c0 + ci]), 0.f);
                v = r0;
            }
            sIn[i] = v;
        }
        for (int i = tid; i < 8192; i += 256) {
            int co = i >> 7, r = i & 127;
            int ci = r >> 4, t = r & 15;
            float v = 0.f;
            if (ci < CC) v = wgt[(((size_t)(coBase + co)) * CIN + (c0 + ci)) * 16 + t];
            sW[r * 64 + (co ^ ((r & 7) << 3))] = v;
        }
        __syncthreads();
        for (int ci = 0; ci < CC; ++ci) {
#pragma unroll
            for (int kh = 0; kh < 4; ++kh) {
#pragma unroll
                for (int kw = 0; kw < 4; ++kw) {
                    const int tap = kh * 4 + kw;
                    const float* wp = sW + (ci * 16 + tap) * 64 + ((cog * 8) ^ ((tap & 7) << 3));
                    float4 wa = *(const float4*)wp;
                    float4 wb = *(const float4*)(wp + 4);
                    const float* ip = sIn + (ci * 18 + rg * 8 + kh) * 34 + tx * 2 + kw;
                    float wv[8] = {wa.x, wa.y, wa.z, wa.w, wb.x, wb.y, wb.z, wb.w};
                    float iv[4] = {ip[0], ip[68], ip[136], ip[204]};
#pragma unroll
                    for (int j = 0; j < 8; ++j)
#pragma unroll
                        for (int r = 0; r < 4; ++r)
                            acc[j][r] = fmaf(wv[j], iv[r], acc[j][r]);
                }
            }
        }
        __syncthreads();
    }

    if (STATS) {
        if (tid < 128) sStat[tid] = 0.f;
        __syncthreads();
    }

    const int coG = coBase + cog * 8;
#pragma unroll
    for (int j = 0; j < 8; ++j) {
        float bv = bias[coG + j];
        float s = 0.f, s2 = 0.f;
#pragma unroll
        for (int r = 0; r < 4; ++r) {
            float v = acc[j][r] + bv;
            if (STORE)
                stv(&out[(((size_t)n * COUT + coG + j) * OH + (oh0 + rg * 4 + r)) * OW + ow0 + tx], v);
            s += v; s2 = fmaf(v, v, s2);
        }
        if (STATS) {
#pragma unroll
            for (int m = 1; m < 16; m <<= 1) {
                s  += __shfl_xor(s, m, 64);
                s2 += __shfl_xor(s2, m, 64);
            }
            if (tx == 0) {
                atomicAdd(&sStat[cog * 8 + j], s);
                atomicAdd(&sStat[64 + cog * 8 + j], s2);
            }
        }
    }
    if (STATS) {
        __syncthreads();
        if (tid < 64) {
            atomicAdd(&gSum[coBase + tid], (double)sStat[tid]);
            atomicAdd(&gSq[coBase + tid],  (double)sStat[64 + tid]);
        }
    }
}

// ---------------- conv 4x4 s2, 8co x 8px tile (tier2) --------
template<int CIN, int COUT, int IH, int IW, int TH, int TW, bool BN_IN,
         bool STORE, bool STATS, typename TI, typename TO>
__global__ __launch_bounds__(256, 3) void conv8K(
    const TI* __restrict__ in, const float* __restrict__ wgt,
    const float* __restrict__ bias,
    const float* __restrict__ inScale, const float* __restrict__ inShift,
    TO* __restrict__ out, double* __restrict__ gSum, double* __restrict__ gSq)
{
    constexpr int OH = IH / 2, OW = IW / 2;
    constexpr int COLB = OW / TW;
    constexpr int SW = TW / 2;
    constexpr int ITH = TH * 2 + 2;
    constexpr int ITWP = TW * 2 + 4;
    constexpr int INSZ = 4 * ITH * ITWP;

    __shared__ float sIn[INSZ];
    __shared__ float sW[4 * 16 * 64];
    __shared__ float sStat[128];

    const int tid = threadIdx.x;
    const int s = tid & 31, cog = tid >> 5;
    const int sw = s & (SW - 1), sh = s / SW;
    const int n = blockIdx.z;
    const int coBase = blockIdx.y * 64;
    const int brow = blockIdx.x / COLB, bcol = blockIdx.x % COLB;
    const int oh0 = brow * TH, ow0 = bcol * TW;
    const int ihb = oh0 * 2 - 1, iwb = ow0 * 2 - 1;

    float acc[8][8];
#pragma unroll
    for (int c = 0; c < 8; ++c)
#pragma unroll
        for (int p = 0; p < 8; ++p) acc[c][p] = 0.f;

    for (int c0 = 0; c0 < CIN; c0 += 4) {
        const int CC = (CIN - c0 < 4) ? (CIN - c0) : 4;
        for (int i = tid; i < INSZ; i += 256) {
            int ci = i / (ITH * ITWP); int rem = i - ci * (ITH * ITWP);
            int ih = rem / ITWP; int iw = rem - ih * ITWP;
            float v = 0.f;
            int gh = ihb + ih, gw = iwb + iw;
            if (ci < CC && (unsigned)gh < (unsigned)IH && (unsigned)gw < (unsigned)IW) {
                float r0 = ldv(&in[(((size_t)n * CIN + (c0 + ci)) * IH + gh) * IW + gw]);
                if (BN_IN) r0 = fmaxf(fmaf(r0, inScale[c0 + ci], inShift[c0 + ci]), 0.f);
                v = r0;
            }
            sIn[i] = v;
        }
        for (int i = tid; i < 4096; i += 256) {
            int r = i >> 6, co = i & 63;
            int ci = r >> 4, tap = r & 15;
            float v = (ci < CC) ? wgt[(((size_t)(coBase + co)) * CIN + (c0 + ci)) * 16 + tap] : 0.f;
            sW[r * 64 + co] = v;
        }
        __syncthreads();
        for (int ci = 0; ci < CC; ++ci) {
#pragma unroll
            for (int kh = 0; kh < 4; ++kh) {
                float inv[4][8];
#pragma unroll
                for (int r = 0; r < 4; ++r) {
                    const float* ip = sIn + (ci * ITH + (sh * 4 + r) * 2 + kh) * ITWP + sw * 4;
                    float4 a = *(const float4*)ip;
                    float4 b = *(const float4*)(ip + 4);
                    inv[r][0] = a.x; inv[r][1] = a.y; inv[r][2] = a.z; inv[r][3] = a.w;
                    inv[r][4] = b.x; inv[r][5] = b.y; inv[r][6] = b.z; inv[r][7] = b.w;
                }
#pragma unroll
                for (int kw = 0; kw < 4; ++kw) {
                    const float* wp = sW + (ci * 16 + kh * 4 + kw) * 64 + cog * 8;
                    float4 wa = *(const float4*)wp;
                    float4 wb = *(const float4*)(wp + 4);
                    float wv[8] = {wa.x, wa.y, wa.z, wa.w, wb.x, wb.y, wb.z, wb.w};
#pragma unroll
                    for (int c = 0; c < 8; ++c)
#pragma unroll
                        for (int r = 0; r < 4; ++r)
#pragma unroll
                            for (int j = 0; j < 2; ++j)
                                acc[c][r * 2 + j] =
                                    fmaf(wv[c], inv[r][2 * j + kw], acc[c][r * 2 + j]);
                }
            }
        }
        __syncthreads();
    }

    if (STATS) {
        if (tid < 128) sStat[tid] = 0.f;
        __syncthreads();
    }

    const int coG = coBase + cog * 8;
#pragma unroll
    for (int c = 0; c < 8; ++c) {
        float bv = bias[coG + c];
        float s1 = 0.f, s2 = 0.f;
#pragma unroll
        for (int p = 0; p < 8; ++p) {
            float v = acc[c][p] + bv;
            int oh = oh0 + sh * 4 + (p >> 1), ow = ow0 + sw * 2 + (p & 1);
            if (STORE)
                stv(&out[(((size_t)n * COUT + coG + c) * OH + oh) * OW + ow], v);
            s1 += v; s2 = fmaf(v, v, s2);
        }
        if (STATS) {
#pragma unroll
            for (int m = 1; m < 32; m <<= 1) {
                s1 += __shfl_xor(s1, m, 64);
                s2 += __shfl_xor(s2, m, 64);
            }
            if ((tid & 31) == 0) {
                atomicAdd(&sStat[cog * 8 + c], s1);
                atomicAdd(&sStat[64 + cog * 8 + c], s2);
            }
        }
    }
    if (STATS) {
        __syncthreads();
        if (tid < 64) {
            atomicAdd(&gSum[coBase + tid], (double)sStat[tid]);
            atomicAdd(&gSq[coBase + tid],  (double)sStat[64 + tid]);
        }
    }
}

// ---------------- BN finalize (tier2, double stats) ----------------
__global__ void bnFinK(const double* __restrict__ gSum, const double* __restrict__ gSq,
                       const float* __restrict__ g, const float* __restrict__ be,
                       float* __restrict__ scale, float* __restrict__ shift,
                       int C, double cnt)
{
    int c = threadIdx.x;
    if (c < C) {
        double m = gSum[c] / cnt;
        double v = gSq[c] / cnt - m * m;
        double sc = (double)g[c] / sqrt(v + 1e-5);
        scale[c] = (float)sc;
        shift[c] = (float)((double)be[c] - m * sc);
    }
}

// ---------------- BN finalize from slot-spread f32 stats ----------------
__global__ void bnFinSlotK(const float* __restrict__ slot,
                           const float* __restrict__ g, const float* __restrict__ be,
                           float* __restrict__ scale, float* __restrict__ shift,
                           int C, double cnt)
{
    int c = threadIdx.x;
    if (c < C) {
        double s = 0.0, s2 = 0.0;
        for (int k = 0; k < NSLOT; ++k) {
            s  += (double)slot[k * 2 * C + c];
            s2 += (double)slot[k * 2 * C + C + c];
        }
        double m = s / cnt;
        double v = s2 / cnt - m * m;
        double sc = (double)g[c] / sqrt(v + 1e-5);
        scale[c] = (float)sc;
        shift[c] = (float)((double)be[c] - m * sc);
    }
}

// ---------------- weight repack: [co][ci][tap] f32 -> [tap][chunk][co][16] f16 ----
__global__ __launch_bounds__(256) void splitWK(
    const float* __restrict__ w, _Float16* __restrict__ wsOut, int CIN, int COUT)
{
    int CH = CIN >> 4;
    int total = 16 * CH * COUT * 16;
    for (int i = blockIdx.x * 256 + threadIdx.x; i < total; i += gridDim.x * 256) {
        int cil = i & 15; int r = i >> 4;
        int co = r % COUT; r /= COUT;
        int c = r % CH; int tap = r / CH;
        int ci = c * 16 + cil;
        wsOut[i] = (_Float16)w[((size_t)co * CIN + ci) * 16 + tap];
    }
}

// ---------------- w1 repack: [co][ci][tap] f32 -> [ci][co][16 taps] f16 ----
__global__ __launch_bounds__(256) void splitW1fK(
    const float* __restrict__ w1, _Float16* __restrict__ w1f)
{
    int i = blockIdx.x * 256 + threadIdx.x;   // 3072
    if (i < 3072) {
        int tap = i & 15; int r = i >> 4;
        int co = r & 63; int ci = r >> 6;
        w1f[i] = (_Float16)w1[((size_t)co * 3 + ci) * 16 + tap];
    }
}

// ---------------- wq repack for MFMA B-operand: [chunk c0][d][16 cil] f16 ----
__global__ __launch_bounds__(256) void splitWqfK(
    const float* __restrict__ wq, _Float16* __restrict__ wqf)
{
    int i = blockIdx.x * 256 + threadIdx.x;   // 16384
    int cil = i & 15; int r = i >> 4;
    int d = r & 63; int c0 = r >> 6;
    wqf[i] = (_Float16)wq[(size_t)d * 256 + c0 * 16 + cil];
}

// ---------------- codebook fp16 copy ----------------
__global__ __launch_bounds__(256) void cbhK(
    const float* __restrict__ cb, _Float16* __restrict__ cbh)
{
    int i = blockIdx.x * 256 + threadIdx.x;   // 32768
    cbh[i] = (_Float16)cb[i];
}

// ---------------- conv1 MFMA: tap-K=16 im2col (3->64) ----------------
__global__ __launch_bounds__(256) void conv1MK(
    const float* __restrict__ x, const _Float16* __restrict__ w1f,
    const float* __restrict__ bias,
    _Float16* __restrict__ out, float* __restrict__ slotS)
{
    constexpr int IH = 256, OH = 128, ITW = 72;
    __shared__ _Float16 sA[3 * 10 * ITW];
    __shared__ float sStat[128];

    const int tid = threadIdx.x;
    const int l = tid & 63, mw = tid >> 6;
    const int lane31 = l & 31, hs = l >> 5;
    const int n = blockIdx.z;
    const int oh0 = (blockIdx.x >> 2) * 4;
    const int owB = (blockIdx.x & 3) * 32;
    const int ghBase = 2 * oh0 - 1, gwA = 2 * owB - 4;

    if (tid < 128) sStat[tid] = 0.f;

    for (int i = tid; i < 540; i += 256) {
        int q = i % 18; int r = i / 18; int ih = r % 10; int ci = r / 10;
        int gh = ghBase + ih;
        int gw0 = gwA + q * 4;
        float vs[4] = {0.f, 0.f, 0.f, 0.f};
        if ((unsigned)gh < (unsigned)IH) {
            const float* src = &x[(((size_t)n * 3 + ci) * IH + gh) * IH + gw0];
            if (gw0 >= 0 && gw0 + 3 < IH) {
                float4 f4 = *(const float4*)src;
                vs[0] = f4.x; vs[1] = f4.y; vs[2] = f4.z; vs[3] = f4.w;
            } else {
#pragma unroll
                for (int e = 0; e < 4; ++e) {
                    int gw = gw0 + e;
                    if ((unsigned)gw < (unsigned)IH) vs[e] = src[e];
                }
            }
        }
        union { _Float16 h[4]; ushort4 u; } t;
        t.h[0] = (_Float16)vs[0]; t.h[1] = (_Float16)vs[1];
        t.h[2] = (_Float16)vs[2]; t.h[3] = (_Float16)vs[3];
        *(ushort4*)&sA[(ci * 10 + ih) * ITW + q * 4] = t.u;
    }
    __syncthreads();

    f32x16 acc[2];
#pragma unroll
    for (int f = 0; f < 2; ++f)
#pragma unroll
        for (int j = 0; j < 16; ++j) acc[f][j] = 0.f;

#pragma unroll
    for (int ci = 0; ci < 3; ++ci) {
        half8 a;
#pragma unroll
        for (int khp = 0; khp < 2; ++khp) {
            const _Float16* row = &sA[(ci * 10 + 2 * mw + 2 * hs + khp) * ITW + 2 * lane31 + 3];
#pragma unroll
            for (int kw = 0; kw < 4; ++kw) a[khp * 4 + kw] = row[kw];
        }
        const _Float16* bp = w1f + ((size_t)ci * 64 + lane31) * 16 + hs * 8;
#pragma unroll
        for (int f = 0; f < 2; ++f) {
            half8 b = *(const half8*)(bp + (size_t)f * 32 * 16);
            acc[f] = __builtin_amdgcn_mfma_f32_32x32x16_f16(a, b, acc[f], 0, 0, 0);
        }
    }

    const int oh = oh0 + mw;
#pragma unroll
    for (int f = 0; f < 2; ++f) {
        int co = f * 32 + lane31;
        float bv = bias[co];
        float s1 = 0.f, s2 = 0.f;
#pragma unroll
        for (int q = 0; q < 4; ++q) {
            float v0 = acc[f][q * 4 + 0] + bv;
            float v1 = acc[f][q * 4 + 1] + bv;
            float v2 = acc[f][q * 4 + 2] + bv;
            float v3 = acc[f][q * 4 + 3] + bv;
            s1 += (v0 + v1) + (v2 + v3);
            s2 = fmaf(v0, v0, s2); s2 = fmaf(v1, v1, s2);
            s2 = fmaf(v2, v2, s2); s2 = fmaf(v3, v3, s2);
            int ow = owB + q * 8 + hs * 4;
            st4(&out[(((size_t)n * 64 + co) * OH + oh) * OH + ow], v0, v1, v2, v3);
        }
        s1 += __shfl_xor(s1, 32, 64);
        s2 += __shfl_xor(s2, 32, 64);
        if (hs == 0) {
            atomicAdd(&sStat[co], s1);
            atomicAdd(&sStat[64 + co], s2);
        }
    }
    __syncthreads();
    float* myslot = slotS + (size_t)((blockIdx.x ^ blockIdx.z) & (NSLOT - 1)) * 128;
    if (tid < 128) atomicAdd(&myslot[tid], sStat[tid]);
}

// ---------------- MFMA conv 4x4 s2 (4-row 8-wave blocks; conv2) ----------------
template<int CIN, int COUT, int IH, int NF, bool BN_IN, typename TO>
__global__ __launch_bounds__(512) void convMfmaK(
    const _Float16* __restrict__ in, const _Float16* __restrict__ wsplit,
    const float* __restrict__ bias,
    const float* __restrict__ inScale, const float* __restrict__ inShift,
    TO* __restrict__ out, float* __restrict__ slotS)
{
    constexpr int OH = IH / 2;
    constexpr int OWB = OH / 32;
    constexpr int CH = CIN / 16;
    constexpr int ROW = 20;
    constexpr int ITW = 72;
    __shared__ _Float16 sA[10 * ITW * ROW];
    __shared__ float sStat[2 * COUT];

    const int tid = threadIdx.x;
    const int l = tid & 63, wid = tid >> 6;
    const int lane31 = l & 31, hs = l >> 5;
    const int mw = wid & 3, nw = wid >> 2;
    const int n = blockIdx.z;
    const int ohB = (blockIdx.x / OWB) * 4;
    const int owB = (blockIdx.x % OWB) * 32;
    const int ghBase = 2 * ohB - 1, gwA = 2 * owB - 4;

    for (int i = tid; i < 2 * COUT; i += 512) sStat[i] = 0.f;

    f32x16 acc[NF];
#pragma unroll
    for (int f = 0; f < NF; ++f)
#pragma unroll
        for (int j = 0; j < 16; ++j) acc[f][j] = 0.f;

    for (int c = 0; c < CH; ++c) {
        __syncthreads();
        for (int i = tid; i < 10 * 18 * 16; i += 512) {
            int iwq = i % 18; int r = i / 18; int ih = r % 10; int cil = r / 10;
            int gh = ghBase + ih;
            int gw0 = gwA + iwq * 4;
            float scv = 1.f, shv = 0.f;
            if (BN_IN) { scv = inScale[c * 16 + cil]; shv = inShift[c * 16 + cil]; }
            float vs[4] = {0.f, 0.f, 0.f, 0.f};
            if ((unsigned)gh < (unsigned)IH) {
                const _Float16* src = &in[(((size_t)n * CIN + c * 16 + cil) * IH + gh) * IH + gw0];
                if (gw0 >= 0 && gw0 + 3 < IH) {
                    half4 q4 = *(const half4*)src;
#pragma unroll
                    for (int e = 0; e < 4; ++e) {
                        float v = (float)q4[e];
                        if (BN_IN) v = fmaxf(fmaf(v, scv, shv), 0.f);
                        vs[e] = v;
                    }
                } else {
#pragma unroll
                    for (int e = 0; e < 4; ++e) {
                        int gw = gw0 + e;
                        if ((unsigned)gw < (unsigned)IH) {
                            float v = (float)src[e];
                            if (BN_IN) v = fmaxf(fmaf(v, scv, shv), 0.f);
                            vs[e] = v;
                        }
                    }
                }
            }
            _Float16* dst = &sA[(ih * ITW + iwq * 4) * ROW + cil];
            dst[0]       = (_Float16)vs[0];
            dst[ROW]     = (_Float16)vs[1];
            dst[2 * ROW] = (_Float16)vs[2];
            dst[3 * ROW] = (_Float16)vs[3];
        }
        __syncthreads();
#pragma unroll
        for (int kh = 0; kh < 4; ++kh) {
#pragma unroll
            for (int kw = 0; kw < 4; ++kw) {
                const int ihX = 2 * mw + kh;
                const int off = (ihX * ITW + 2 * lane31 + kw + 3) * ROW + hs * 8;
                half4 a0 = *(const half4*)&sA[off];
                half4 a1 = *(const half4*)&sA[off + 4];
                half8 a;
                a[0] = a0[0]; a[1] = a0[1]; a[2] = a0[2]; a[3] = a0[3];
                a[4] = a1[0]; a[5] = a1[1]; a[6] = a1[2]; a[7] = a1[3];
                const _Float16* bp = wsplit
                    + (((size_t)(kh * 4 + kw) * CH + c) * COUT + nw * (NF * 32) + lane31) * 16
                    + hs * 8;
#pragma unroll
                for (int f = 0; f < NF; ++f) {
                    half8 b = *(const half8*)(bp + (size_t)f * 32 * 16);
                    acc[f] = __builtin_amdgcn_mfma_f32_32x32x16_f16(a, b, acc[f], 0, 0, 0);
                }
            }
        }
    }

    const int oh = ohB + mw;
#pragma unroll
    for (int f = 0; f < NF; ++f) {
        int co = nw * (NF * 32) + f * 32 + lane31;
        float bv = bias[co];
        float s1 = 0.f, s2 = 0.f;
#pragma unroll
        for (int q = 0; q < 4; ++q) {
            float v0 = acc[f][q * 4 + 0] + bv;
            float v1 = acc[f][q * 4 + 1] + bv;
            float v2 = acc[f][q * 4 + 2] + bv;
            float v3 = acc[f][q * 4 + 3] + bv;
            s1 += (v0 + v1) + (v2 + v3);
            s2 = fmaf(v0, v0, s2); s2 = fmaf(v1, v1, s2);
            s2 = fmaf(v2, v2, s2); s2 = fmaf(v3, v3, s2);
            int ow = owB + q * 8 + hs * 4;
            st4(&out[(((size_t)n * COUT + co) * OH + oh) * OH + ow], v0, v1, v2, v3);
        }
        s1 += __shfl_xor(s1, 32, 64);
        s2 += __shfl_xor(s2, 32, 64);
        if (hs == 0) {
            atomicAdd(&sStat[co], s1);
            atomicAdd(&sStat[COUT + co], s2);
        }
    }
    __syncthreads();
    float* myslot = slotS + (size_t)((blockIdx.x ^ blockIdx.z) & (NSLOT - 1)) * (2 * COUT);
    for (int i = tid; i < 2 * COUT; i += 512) atomicAdd(&myslot[i], sStat[i]);
}

// ---------------- MFMA conv 4x4 s2 (1-row 4-wave blocks; conv3) ----------------
template<int CIN, int COUT, int IH, int OWBn, int NF, bool BN_IN, typename TO>
__global__ __launch_bounds__(256) void convM1RK(
    const _Float16* __restrict__ in, const _Float16* __restrict__ wsplit,
    const float* __restrict__ bias,
    const float* __restrict__ inScale, const float* __restrict__ inShift,
    TO* __restrict__ out, float* __restrict__ slotS)
{
    constexpr int OH = IH / 2;
    constexpr int CH = CIN / 16;
    constexpr int ROW = 20;
    constexpr int ITW = 72;
    __shared__ _Float16 sA[4 * ITW * ROW];
    __shared__ float sStat[2 * COUT];

    const int tid = threadIdx.x;
    const int l = tid & 63, nw = tid >> 6;
    const int lane31 = l & 31, hs = l >> 5;
    const int n = blockIdx.z;
    const int oh = blockIdx.x / OWBn;
    const int owB = (blockIdx.x % OWBn) * 32;
    const int ghBase = 2 * oh - 1, gwA = 2 * owB - 4;

    for (int i = tid; i < 2 * COUT; i += 256) sStat[i] = 0.f;

    f32x16 acc[NF];
#pragma unroll
    for (int f = 0; f < NF; ++f)
#pragma unroll
        for (int j = 0; j < 16; ++j) acc[f][j] = 0.f;

    for (int c = 0; c < CH; ++c) {
        __syncthreads();
        for (int i = tid; i < 4 * 18 * 16; i += 256) {
            int iwq = i % 18; int r = i / 18; int ih = r & 3; int cil = r >> 2;
            int gh = ghBase + ih;
            int gw0 = gwA + iwq * 4;
            float scv = 1.f, shv = 0.f;
            if (BN_IN) { scv = inScale[c * 16 + cil]; shv = inShift[c * 16 + cil]; }
            float vs[4] = {0.f, 0.f, 0.f, 0.f};
            if ((unsigned)gh < (unsigned)IH) {
                const _Float16* src = &in[(((size_t)n * CIN + c * 16 + cil) * IH + gh) * IH + gw0];
                if (gw0 >= 0 && gw0 + 3 < IH) {
                    half4 q4 = *(const half4*)src;
#pragma unroll
                    for (int e = 0; e < 4; ++e) {
                        float v = (float)q4[e];
                        if (BN_IN) v = fmaxf(fmaf(v, scv, shv), 0.f);
                        vs[e] = v;
                    }
                } else {
#pragma unroll
                    for (int e = 0; e < 4; ++e) {
                        int gw = gw0 + e;
                        if ((unsigned)gw < (unsigned)IH) {
                            float v = (float)src[e];
                            if (BN_IN) v = fmaxf(fmaf(v, scv, shv), 0.f);
                            vs[e] = v;
                        }
                    }
                }
            }
            _Float16* dst = &sA[(ih * ITW + iwq * 4) * ROW + cil];
            dst[0]       = (_Float16)vs[0];
            dst[ROW]     = (_Float16)vs[1];
            dst[2 * ROW] = (_Float16)vs[2];
            dst[3 * ROW] = (_Float16)vs[3];
        }
        __syncthreads();
#pragma unroll
        for (int kh = 0; kh < 4; ++kh) {
#pragma unroll
            for (int kw = 0; kw < 4; ++kw) {
                const int off = (kh * ITW + 2 * lane31 + kw + 3) * ROW + hs * 8;
                half4 a0 = *(const half4*)&sA[off];
                half4 a1 = *(const half4*)&sA[off + 4];
                half8 a;
                a[0] = a0[0]; a[1] = a0[1]; a[2] = a0[2]; a[3] = a0[3];
                a[4] = a1[0]; a[5] = a1[1]; a[6] = a1[2]; a[7] = a1[3];
                const _Float16* bp = wsplit
                    + (((size_t)(kh * 4 + kw) * CH + c) * COUT + nw * (NF * 32) + lane31) * 16
                    + hs * 8;
#pragma unroll
                for (int f = 0; f < NF; ++f) {
                    half8 b = *(const half8*)(bp + (size_t)f * 32 * 16);
                    acc[f] = __builtin_amdgcn_mfma_f32_32x32x16_f16(a, b, acc[f], 0, 0, 0);
                }
            }
        }
    }

#pragma unroll
    for (int f = 0; f < NF; ++f) {
        int co = nw * (NF * 32) + f * 32 + lane31;
        float bv = bias[co];
        float s1 = 0.f, s2 = 0.f;
#pragma unroll
        for (int q = 0; q < 4; ++q) {
            float v0 = acc[f][q * 4 + 0] + bv;
            float v1 = acc[f][q * 4 + 1] + bv;
            float v2 = acc[f][q * 4 + 2] + bv;
            float v3 = acc[f][q * 4 + 3] + bv;
            s1 += (v0 + v1) + (v2 + v3);
            s2 = fmaf(v0, v0, s2); s2 = fmaf(v1, v1, s2);
            s2 = fmaf(v2, v2, s2); s2 = fmaf(v3, v3, s2);
            int ow = owB + q * 8 + hs * 4;
            st4(&out[(((size_t)n * COUT + co) * OH + oh) * OH + ow], v0, v1, v2, v3);
        }
        s1 += __shfl_xor(s1, 32, 64);
        s2 += __shfl_xor(s2, 32, 64);
        if (hs == 0) {
            atomicAdd(&sStat[co], s1);
            atomicAdd(&sStat[COUT + co], s2);
        }
    }
    __syncthreads();
    float* myslot = slotS + (size_t)((blockIdx.x ^ blockIdx.z) & (NSLOT - 1)) * (2 * COUT);
    for (int i = tid; i < 2 * COUT; i += 256) atomicAdd(&myslot[i], sStat[i]);
}

// ---------------- fused head v4: MFMA z-GEMM + score-GEMM ----------------
__global__ __launch_bounds__(512) void headK4(
    const _Float16* __restrict__ y3h, const _Float16* __restrict__ wqf,
    const float* __restrict__ bq,
    const float* __restrict__ sc3, const float* __restrict__ sh3,
    const float* __restrict__ cb, const _Float16* __restrict__ cbh,
    const float* __restrict__ csqf,
    float* __restrict__ out, int* __restrict__ counts,
    double* __restrict__ lossAcc)
{
    __shared__ _Float16 sH[32 * 264];
    __shared__ float    sZ[32 * 68];
    __shared__ _Float16 sZh[32 * 72];
    __shared__ float    sCS[8 * 32];
    __shared__ int      sCI[8 * 32];

    const int tid = threadIdx.x;
    const int w = tid >> 6;
    const int l = tid & 63;
    const int lane31 = l & 31, hs = l >> 5;
    const int blk = blockIdx.x;
    const int n = (blk * 32) >> 10;
    const int hw0 = (blk * 32) & 1023;

    {
        const int px = tid & 31, cg = tid >> 5;
#pragma unroll
        for (int k = 0; k < 16; ++k) {
            int c = cg + 16 * k;
            float v = (float)y3h[(((size_t)n * 256 + c) << 10) + hw0 + px];
            v = fmaxf(fmaf(v, sc3[c], sh3[c]), 0.f);
            sH[px * 264 + c] = (_Float16)v;
        }
    }
    __syncthreads();

    if (w < 2) {
        f32x16 za;
#pragma unroll
        for (int j = 0; j < 16; ++j) za[j] = 0.f;
#pragma unroll
        for (int c0 = 0; c0 < 16; ++c0) {
            half8 a = *(const half8*)&sH[lane31 * 264 + c0 * 16 + hs * 8];
            const _Float16* bp = wqf + ((size_t)(c0 * 64) + 32 * w + lane31) * 16 + hs * 8;
            half8 b = *(const half8*)bp;
            za = __builtin_amdgcn_mfma_f32_32x32x16_f16(a, b, za, 0, 0, 0);
        }
        const int d = 32 * w + lane31;
        const float bqv = bq[d];
#pragma unroll
        for (int j = 0; j < 16; ++j) {
            int row = (j & 3) + 8 * (j >> 2) + 4 * hs;
            float zv = za[j] + bqv;
            sZ[row * 68 + d] = zv;
            sZh[row * 72 + d] = (_Float16)zv;
        }
    }
    __syncthreads();

    f32x16 acc0, acc1;
#pragma unroll
    for (int j = 0; j < 16; ++j) { acc0[j] = 0.f; acc1[j] = 0.f; }
#pragma unroll
    for (int ks = 0; ks < 4; ++ks) {
        half8 a = *(const half8*)&sZh[lane31 * 72 + ks * 16 + hs * 8];
        const _Float16* b0 = cbh + ((size_t)(64 * w + lane31) << 6) + ks * 16 + hs * 8;
        const _Float16* b1 = b0 + (32 << 6);
        acc0 = __builtin_amdgcn_mfma_f32_32x32x16_f16(a, *(const half8*)b0, acc0, 0, 0, 0);
        acc1 = __builtin_amdgcn_mfma_f32_32x32x16_f16(a, *(const half8*)b1, acc1, 0, 0, 0);
    }
    const int cw0 = 64 * w + lane31;
    const float cs0 = csqf[cw0], cs1 = csqf[cw0 + 32];
#pragma unroll
    for (int j = 0; j < 16; ++j) {
        int row = (j & 3) + 8 * (j >> 2) + 4 * hs;
        float s = cs0 - 2.f * acc0[j];
        int idx = cw0;
        float s1 = cs1 - 2.f * acc1[j];
        if (s1 < s) { s = s1; idx = cw0 + 32; }
#pragma unroll
        for (int m = 1; m < 32; m <<= 1) {
            float so = __shfl_xor(s, m, 32);
            int io = __shfl_xor(idx, m, 32);
            if (so < s || (so == s && io < idx)) { s = so; idx = io; }
        }
        if (lane31 == 0) { sCS[w * 32 + row] = s; sCI[w * 32 + row] = idx; }
    }
    __syncthreads();

    if (w == 0 && l < 32) {
        const int px = l;
        float best = sCS[px]; int bidx = sCI[px];
#pragma unroll
        for (int g = 1; g < 8; ++g) {
            float b = sCS[g * 32 + px]; int i = sCI[g * 32 + px];
            if (b < best || (b == best && i < bidx)) { best = b; bidx = i; }
        }
        atomicAdd(&counts[bidx], 1);

        const int hw = hw0 + px;
        const int hh = hw >> 5, ww = hw & 31;
        const int obase = n * CHW + (hh + 1) * 34 + (ww + 1);
        const float4* qp = (const float4*)(cb + ((size_t)bidx << 6));
        const float4* zrow = (const float4*)(sZ + px * 68);
        float sq = 0.f;
#pragma unroll
        for (int q = 0; q < 16; ++q) {
            float4 c4 = qp[q];
            float4 z4 = zrow[q];
            float d0 = c4.x - z4.x, d1 = c4.y - z4.y;
            float d2 = c4.z - z4.z, d3 = c4.w - z4.w;
            sq = fmaf(d0, d0, sq); sq = fmaf(d1, d1, sq);
            sq = fmaf(d2, d2, sq); sq = fmaf(d3, d3, sq);
            out[obase + (4 * q + 0) * HW2] = c4.x;
            out[obase + (4 * q + 1) * HW2] = c4.y;
            out[obase + (4 * q + 2) * HW2] = c4.z;
            out[obase + (4 * q + 3) * HW2] = c4.w;
        }
#pragma unroll
        for (int m = 1; m < 32; m <<= 1) sq += __shfl_xor(sq, m, 32);
        if (l == 0) atomicAdd(lossAcc, (double)sq);
    }
}

// ---------------- tier2: 1x1 conv kernel ----------------
__global__ __launch_bounds__(128) void convqK(
    const float* __restrict__ y3, const float* __restrict__ wq,
    const float* __restrict__ bq,
    const float* __restrict__ sc3, const float* __restrict__ sh3,
    float* __restrict__ z)
{
    __shared__ float sWq[64 * 68];
    __shared__ float sS[64], sH[64];
    const int tid = threadIdx.x;
    const int px = blockIdx.x * 128 + tid;
    const int n = px >> 10, hw = px & 1023;

    float accv[64];
#pragma unroll
    for (int d = 0; d < 64; ++d) accv[d] = 0.f;

    const float* base = y3 + (((size_t)n * 256) << 10) + hw;
    for (int c0 = 0; c0 < 256; c0 += 64) {
        __syncthreads();
        for (int i = tid; i < 4096; i += 128) {
            int c = i & 63, d = i >> 6;
            sWq[c * 68 + d] = wq[(size_t)d * 256 + c0 + c];
        }
        if (tid < 64) { sS[tid] = sc3[c0 + tid]; sH[tid] = sh3[c0 + tid]; }
        __syncthreads();
        for (int c = 0; c < 64; ++c) {
            float h = base[(size_t)(c0 + c) << 10];
            h = fmaxf(fmaf(h, sS[c], sH[c]), 0.f);
            const float4* wrow = (const float4*)(sWq + c * 68);
#pragma unroll
            for (int q = 0; q < 16; ++q) {
                float4 w4 = wrow[q];
                accv[4*q+0] = fmaf(h, w4.x, accv[4*q+0]);
                accv[4*q+1] = fmaf(h, w4.y, accv[4*q+1]);
                accv[4*q+2] = fmaf(h, w4.z, accv[4*q+2]);
                accv[4*q+3] = fmaf(h, w4.w, accv[4*q+3]);
            }
        }
    }
    float* zo = z + (size_t)px * 64;
    const float4* bq4 = (const float4*)bq;
#pragma unroll
    for (int q = 0; q < 16; ++q) {
        float4 b4 = bq4[q];
        float4 v;
        v.x = accv[4*q+0] + b4.x; v.y = accv[4*q+1] + b4.y;
        v.z = accv[4*q+2] + b4.z; v.w = accv[4*q+3] + b4.w;
        ((float4*)zo)[q] = v;
    }
}

// ---------------- tier2: vq kernel ----------------
__global__ __launch_bounds__(256) void vqK(
    const float* __restrict__ z, const float* __restrict__ cb,
    const float* __restrict__ csqf, float* __restrict__ out,
    int* __restrict__ counts, double* __restrict__ lossAcc)
{
    const int tid = threadIdx.x;
    const int lane = tid & 63;
    const int grp = tid >> 6;
    const int px = blockIdx.x * 64 + lane;

    float zr[64];
    const float4* zp = (const float4*)(z + (size_t)px * 64);
#pragma unroll
    for (int q = 0; q < 16; ++q) {
        float4 t = zp[q];
        zr[4*q] = t.x; zr[4*q+1] = t.y; zr[4*q+2] = t.z; zr[4*q+3] = t.w;
    }

    const int kbase = grp * 128;
    float best = 3.4e38f; int bidx = kbase;
    for (int kk = 0; kk < 128; ++kk) {
        const float4* crow = (const float4*)(cb + (size_t)(kbase + kk) * 64);
        float d0 = 0.f, d1 = 0.f, d2 = 0.f, d3 = 0.f;
#pragma unroll
        for (int q = 0; q < 16; ++q) {
            float4 c4 = crow[q];
            d0 = fmaf(zr[4*q+0], c4.x, d0);
            d1 = fmaf(zr[4*q+1], c4.y, d1);
            d2 = fmaf(zr[4*q+2], c4.z, d2);
            d3 = fmaf(zr[4*q+3], c4.w, d3);
        }
        float dot = (d0 + d1) + (d2 + d3);
        float score = csqf[kbase + kk] - 2.0f * dot;
        if (score < best) { best = score; bidx = kbase + kk; }
    }

    __shared__ float sB[256];
    __shared__ int   sI[256];
    sB[tid] = best; sI[tid] = bidx;
    __syncthreads();
    if (grp == 0) {
#pragma unroll
        for (int g = 1; g < 4; ++g) {
            float b = sB[lane + 64 * g]; int i = sI[lane + 64 * g];
            if (b < best || (b == best && i < bidx)) { best = b; bidx = i; }
        }
        atomicAdd(&counts[bidx], 1);

        const int n = px >> 10, hw = px & 1023;
        const int h = hw >> 5, w = hw & 31;
        const int obase = n * CHW + (h + 1) * 34 + (w + 1);
        const float4* qp = (const float4*)(cb + (size_t)bidx * 64);
        float sq = 0.f;
#pragma unroll
        for (int q = 0; q < 16; ++q) {
            float4 c4 = qp[q];
            float vv[4] = {c4.x, c4.y, c4.z, c4.w};
#pragma unroll
            for (int j = 0; j < 4; ++j) {
                int d = 4 * q + j;
                float df = vv[j] - zr[d];
                sq = fmaf(df, df, sq);
                out[obase + d * HW2] = vv[j];
            }
        }
#pragma unroll
        for (int m = 1; m < 64; m <<= 1) sq += __shfl_xor(sq, m, 64);
        if (lane == 0) atomicAdd(lossAcc, (double)sq);
    }
}

// ---------------- loss + perplexity ----------------
__global__ void finalizeK(const int* __restrict__ counts,
                          const double* __restrict__ lossAcc,
                          float* __restrict__ out)
{
    const int tid = threadIdx.x;
    double ent = 0.0;
    for (int k = tid; k < 512; k += 64) {
        double p = (double)counts[k] / NPX;
        ent -= p * log(p + 1e-10);
    }
#pragma unroll
    for (int m = 1; m < 64; m <<= 1) ent += __shfl_xor(ent, m, 64);
    if (tid == 0) {
        out[SYM_N]     = (float)(1.25 * lossAcc[0] / (double)SYM_N);
        out[SYM_N + 1] = (float)exp(ent);
    }
}

// ---------------- fallback: zero + sentinel ----------------
__global__ __launch_bounds__(256) void zeroOutK(float* __restrict__ out, int n) {
    int i = blockIdx.x * 256 + threadIdx.x;
    if (i < n) out[i] = 0.0f;
}
__global__ void sentinelK(float* out, float lossv, float perpv) {
    if (threadIdx.x == 0) { out[SYM_N] = lossv; out[SYM_N + 1] = perpv; }
}

// =======================================================================
// primary path
// =======================================================================
static void run_mfma(void* const* d_in, float* out, char* ws, hipStream_t stream)
{
    const float* x   = (const float*)d_in[0];
    const float* w1  = (const float*)d_in[1];
    const float* b1  = (const float*)d_in[2];
    const float* g1  = (const float*)d_in[3];
    const float* be1 = (const float*)d_in[4];
    const float* w2  = (const float*)d_in[5];
    const float* b2  = (const float*)d_in[6];
    const float* g2  = (const float*)d_in[7];
    const float* be2 = (const float*)d_in[8];
    const float* w3  = (const float*)d_in[9];
    const float* b3  = (const float*)d_in[10];
    const float* g3  = (const float*)d_in[11];
    const float* be3 = (const float*)d_in[12];
    const float* wq  = (const float*)d_in[13];
    const float* bq  = (const float*)d_in[14];
    const float* cb  = (const float*)d_in[15];

    double* statd  = (double*)(ws);
    float*  sscale = (float*)(ws + 16384);
    int*    counts = (int*)(ws + 24576);
    float*  csqf   = (float*)(ws + 28672);
    double* csqd   = (double*)(ws + 30720);
    int*    kbord  = (int*)(ws + 34816);
    double* lossAcc = statd + 1536;

    char* A0 = ws + 65536;
    _Float16* y1h = (_Float16*)A0;                         // 64MB
    _Float16* y2h = (_Float16*)(A0 + 67108864ull);         // 32MB
    _Float16* y3h = (_Float16*)(A0 + 100663296ull);        // 16MB
    _Float16* w2s = (_Float16*)(A0 + 117440512ull);        // 256KB
    _Float16* w3s = (_Float16*)(A0 + 117702656ull);        // 1MB
    _Float16* wqf = (_Float16*)(A0 + 118751232ull);        // 32KB
    _Float16* cbh = (_Float16*)(A0 + 118800384ull);        // 64KB
    _Float16* w1f = (_Float16*)(A0 + 118865920ull);        // 6KB
    float*    slot1 = (float*)(A0 + 119013376ull);         // 16*128 f  (8KB)
    float*    slot2 = slot1 + NSLOT * 128;                 // 16*256 f  (16KB)
    float*    slot3 = slot2 + NSLOT * 256;                 // 16*512 f  (32KB)
    // total slots = 16*(128+256+512) = 14336 floats

    initStatsK<<<7, 256, 0, stream>>>(statd, counts);
    zeroSlotsK<<<56, 256, 0, stream>>>(slot1, NSLOT * (128 + 256 + 512));
    csqK<<<2, 256, 0, stream>>>(cb, csqf, csqd);
    borderK<<<1, 512, 0, stream>>>(csqd, kbord, counts, lossAcc);
    fillK<<<(SYM_N + 255) / 256, 256, 0, stream>>>(kbord, cb, out);
    splitWK<<<512, 256, 0, stream>>>(w2, w2s, 64, 128);
    splitWK<<<2048, 256, 0, stream>>>(w3, w3s, 128, 256);
    splitWqfK<<<64, 256, 0, stream>>>(wq, wqf);
    cbhK<<<128, 256, 0, stream>>>(cb, cbh);
    splitW1fK<<<12, 256, 0, stream>>>(w1, w1f);

    conv1MK<<<dim3(128, 1, BATCH), 256, 0, stream>>>(
        x, w1f, b1, y1h, slot1);
    bnFinSlotK<<<1, 256, 0, stream>>>(slot1, g1, be1,
                                      sscale + 0, sscale + 256, 64, 524288.0);

    convMfmaK<64, 128, 128, 2, true, _Float16>
        <<<dim3(32, 1, BATCH), 512, 0, stream>>>(
        y1h, w2s, b2, sscale + 0, sscale + 256, y2h, slot2);
    bnFinSlotK<<<1, 256, 0, stream>>>(slot2, g2, be2,
                                      sscale + 512, sscale + 768, 128, 131072.0);

    convM1RK<128, 256, 64, 1, 2, true, _Float16>
        <<<dim3(32, 1, BATCH), 256, 0, stream>>>(
        y2h, w3s, b3, sscale + 512, sscale + 768, y3h, slot3);
    bnFinSlotK<<<1, 256, 0, stream>>>(slot3, g3, be3,
                                      sscale + 1024, sscale + 1280, 256, 32768.0);

    headK4<<<1024, 512, 0, stream>>>(y3h, wqf, bq, sscale + 1024, sscale + 1280,
                                     cb, cbh, csqf, out, counts, lossAcc);
    finalizeK<<<1, 64, 0, stream>>>(counts, lossAcc, out);
}

// =======================================================================
// fallback tier2: single-pass bf16 storage (proven structure)
// =======================================================================
static void run_fast_bf16(void* const* d_in, float* out, char* ws, hipStream_t stream)
{
    const float* x   = (const float*)d_in[0];
    const float* w1  = (const float*)d_in[1];
    const float* b1  = (const float*)d_in[2];
    const float* g1  = (const float*)d_in[3];
    const float* be1 = (const float*)d_in[4];
    const float* w2  = (const float*)d_in[5];
    const float* b2  = (const float*)d_in[6];
    const float* g2  = (const float*)d_in[7];
    const float* be2 = (const float*)d_in[8];
    const float* w3  = (const float*)d_in[9];
    const float* b3  = (const float*)d_in[10];
    const float* g3  = (const float*)d_in[11];
    const float* be3 = (const float*)d_in[12];
    const float* wq  = (const float*)d_in[13];
    const float* bq  = (const float*)d_in[14];
    const float* cb  = (const float*)d_in[15];

    double* statd  = (double*)(ws);
    float*  sscale = (float*)(ws + 16384);
    int*    counts = (int*)(ws + 24576);
    float*  csqf   = (float*)(ws + 28672);
    double* csqd   = (double*)(ws + 30720);
    int*    kbord  = (int*)(ws + 34816);
    double* lossAcc = statd + 1536;

    __hip_bfloat16* y1 = (__hip_bfloat16*)(ws + 65536);
    __hip_bfloat16* y2 = (__hip_bfloat16*)(ws + 65536 + 67108864ull);
    float* y3 = (float*)(ws + 65536);
    float* z  = (float*)(ws + 65536 + 33554432ull);

    initStatsK<<<7, 256, 0, stream>>>(statd, counts);
    csqK<<<2, 256, 0, stream>>>(cb, csqf, csqd);
    borderK<<<1, 512, 0, stream>>>(csqd, kbord, counts, lossAcc);
    fillK<<<(SYM_N + 255) / 256, 256, 0, stream>>>(kbord, cb, out);

    conv4x4s2K<3, 64, 256, 256, false, true, true, float, __hip_bfloat16>
        <<<dim3(128, 1, BATCH), 256, 0, stream>>>(
        x, w1, b1, nullptr, nullptr, y1, statd + 0, statd + 256);
    bnFinK<<<1, 256, 0, stream>>>(statd + 0, statd + 256, g1, be1,
                                  sscale + 0, sscale + 256, 64, 524288.0);

    conv8K<64, 128, 128, 128, 8, 32, true, true, true, __hip_bfloat16, __hip_bfloat16>
        <<<dim3(16, 2, BATCH), 256, 0, stream>>>(
        y1, w2, b2, sscale + 0, sscale + 256, y2, statd + 512, statd + 768);
    bnFinK<<<1, 256, 0, stream>>>(statd + 512, statd + 768, g2, be2,
                                  sscale + 512, sscale + 768, 128, 131072.0);

    conv8K<128, 256, 64, 64, 16, 16, true, true, true, __hip_bfloat16, float>
        <<<dim3(4, 4, BATCH), 256, 0, stream>>>(
        y2, w3, b3, sscale + 512, sscale + 768, y3, statd + 1024, statd + 1280);
    bnFinK<<<1, 256, 0, stream>>>(statd + 1024, statd + 1280, g3, be3,
                                  sscale + 1024, sscale + 1280, 256, 32768.0);

    convqK<<<256, 128, 0, stream>>>(y3, wq, bq, sscale + 1024, sscale + 1280, z);
    vqK<<<512, 256, 0, stream>>>(z, cb, csqf, out, counts, lossAcc);
    finalizeK<<<1, 64, 0, stream>>>(counts, lossAcc, out);
}

extern "C" void kernel_launch(void* const* d_in, const int* in_sizes, int n_in,
                              void* d_out, int out_size, void* d_ws, size_t ws_size,
                              hipStream_t stream)
{
    float* out = (float*)d_out;
    char* ws = (char*)d_ws;

    if (ws_size >= NEED1) {
        run_mfma(d_in, out, ws, stream);
    } else if (ws_size >= NEED2) {
        run_fast_bf16(d_in, out, ws, stream);
    } else {
        zeroOutK<<<(SYM_N + 2 + 255) / 256, 256, 0, stream>>>(out, SYM_N + 2);
        sentinelK<<<1, 64, 0, stream>>>(out, -4444.0f, -5555.0f);
    }
}